// Round 15
// baseline (457.911 us; speedup 1.0000x reference)
//
#include <hip/hip_runtime.h>
#include <math.h>

// Problem constants (fixed-shape problem)
#define DD 256
#define HH 4
#define CC 64
#define LL 5
#define NEG_SLOPE 0.2f
#define LH 20   // L*H
#define WCAP 192  // per-wave LDS softmax-weight cache

typedef __bf16 bf16x8 __attribute__((ext_vector_type(8)));
typedef __bf16 bf16x4 __attribute__((ext_vector_type(4)));
typedef float f32x4 __attribute__((ext_vector_type(4)));

static __device__ __forceinline__ float lrelu(float x) {
    return x > 0.0f ? x : NEG_SLOPE * x;
}

// ---------------------------------------------------------------------------
// K0: wproj (single block) then pack edge-encoder + wproj B-fragments (bf16).
__global__ __launch_bounds__(256) void edge_setup_kernel(
    const float* __restrict__ gat_ew, const float* __restrict__ att_edge,
    const float* __restrict__ eenc_w, const float* __restrict__ eenc_b,
    float* __restrict__ wproj, __bf16* __restrict__ wfe,
    __bf16* __restrict__ wfp) {
    int tid = threadIdx.x;
    int k = tid;
    for (int l = 0; l < LL; ++l) {
        const float* W = gat_ew + (size_t)l * DD * DD;
        const float* att = att_edge + l * DD;
        for (int hh = 0; hh < HH; ++hh) {
            float s = 0.f;
            #pragma unroll
            for (int c = 0; c < CC; ++c)
                s += W[k * DD + hh * CC + c] * att[hh * CC + c];
            wproj[k * LH + l * HH + hh] = s;
        }
    }
    __syncthreads();
    for (int idx = tid; idx < 16 * 64; idx += 256) {
        int t = idx >> 6, lane = idx & 63;
        int q = lane >> 4, r15 = lane & 15;
        int col = t * 16 + r15;
        #pragma unroll
        for (int j = 0; j < 8; ++j) {
            int kk = q * 8 + j;
            float v = (kk < 12) ? eenc_w[kk * 256 + col]
                                : (kk == 12 ? eenc_b[col] : 0.f);
            wfe[(size_t)idx * 8 + j] = (__bf16)v;
        }
    }
    for (int idx = tid; idx < 16 * 64; idx += 256) {
        int sidx = idx >> 6, lane = idx & 63;
        int s = sidx >> 1, t2 = sidx & 1;
        int q = lane >> 4, r15 = lane & 15;
        int col = t2 * 16 + r15;
        #pragma unroll
        for (int j = 0; j < 8; ++j) {
            int kk = s * 32 + q * 8 + j;
            float v = (col < LH) ? wproj[kk * LH + col] : 0.f;
            wfp[(size_t)idx * 8 + j] = (__bf16)v;
        }
    }
}

// ---------------------------------------------------------------------------
// K0c: swizzle GEMM weights into MFMA B-fragment order, bf16.
__global__ __launch_bounds__(256) void wswizzle_kernel(
    const float* __restrict__ gat_w, const float* __restrict__ gate_w1,
    __bf16* __restrict__ wf) {
    int b = blockIdx.x;           // l*32 + y*8 + ks
    int l = b >> 5;
    int rem = b & 31;
    int y = rem >> 3, ks = rem & 7;
    int tid = threadIdx.x;
    int t = tid >> 6, lane = tid & 63;
    int q = lane >> 4, r15 = lane & 15;
    const float* W = (l < 5) ? (gat_w + (size_t)l * DD * DD) : gate_w1;
    size_t obase = (((size_t)b * 4 + t) * 64 + lane) * 8;
    int kbase = ks * 32 + q * 8;
    int col = y * 64 + t * 16 + r15;
    #pragma unroll
    for (int j = 0; j < 8; ++j)
        wf[obase + j] = (__bf16)W[(size_t)(kbase + j) * DD + col];
}

// ---------------------------------------------------------------------------
// K1: node encoder h = relu(x @ enc_w + enc_b); also writes bf16 shadow
__global__ __launch_bounds__(256) void encoder_kernel(
    const float* __restrict__ x, const float* __restrict__ enc_w,
    const float* __restrict__ enc_b, float* __restrict__ h,
    __bf16* __restrict__ hbf, int N) {
    int n = blockIdx.x;
    int tid = threadIdx.x;
    __shared__ float xs[42];
    if (tid < 42) xs[tid] = x[(size_t)n * 42 + tid];
    __syncthreads();
    float acc = enc_b[tid];
    #pragma unroll
    for (int f = 0; f < 42; ++f) acc += xs[f] * enc_w[f * DD + tid];
    float v = fmaxf(acc, 0.f);
    h[(size_t)n * DD + tid] = v;
    hbf[(size_t)n * DD + tid] = (__bf16)v;
}

// ---------------------------------------------------------------------------
// K2 v6: edge_pre on matrix cores; output in CSR order via pos[e].
__global__ __launch_bounds__(256) void edge_mfma_kernel(
    const float* __restrict__ edge_attr, const __bf16* __restrict__ wfe,
    const __bf16* __restrict__ wfp, const int* __restrict__ pos,
    float* __restrict__ a_e_csr, int E) {
    __shared__ __bf16 sm[4][16][264];   // 33 KB
    int tid = threadIdx.x;
    int w = tid >> 6, lane = tid & 63;
    int q = lane >> 4, r15 = lane & 15;
    int eb = blockIdx.x * 64 + w * 16;
    int e = eb + r15;
    int ec = min(e, E - 1);
    bf16x8 a1;
    #pragma unroll
    for (int j = 0; j < 8; ++j) a1[j] = (__bf16)0.f;
    if (q == 0) {
        const float4* p = (const float4*)(edge_attr + (size_t)ec * 12);
        float4 p0 = p[0], p1 = p[1];
        a1[0] = (__bf16)p0.x; a1[1] = (__bf16)p0.y; a1[2] = (__bf16)p0.z; a1[3] = (__bf16)p0.w;
        a1[4] = (__bf16)p1.x; a1[5] = (__bf16)p1.y; a1[6] = (__bf16)p1.z; a1[7] = (__bf16)p1.w;
    } else if (q == 1) {
        float4 p2 = *(const float4*)(edge_attr + (size_t)ec * 12 + 8);
        a1[0] = (__bf16)p2.x; a1[1] = (__bf16)p2.y; a1[2] = (__bf16)p2.z; a1[3] = (__bf16)p2.w;
        a1[4] = (__bf16)1.0f;  // k = 12: bias row
    }
    const bf16x8* wfeP = (const bf16x8*)wfe;
    f32x4 zero = (f32x4){0.f, 0.f, 0.f, 0.f};
    #pragma unroll
    for (int t = 0; t < 16; ++t) {
        bf16x8 bfr = wfeP[t * 64 + lane];
        f32x4 c = __builtin_amdgcn_mfma_f32_16x16x32_bf16(a1, bfr, zero, 0, 0, 0);
        int col = t * 16 + r15;
        #pragma unroll
        for (int r = 0; r < 4; ++r)
            sm[w][q * 4 + r][col] = (__bf16)fmaxf(c[r], 0.f);
    }
    const bf16x8* wfpP = (const bf16x8*)wfp;
    f32x4 c2[2];
    c2[0] = zero; c2[1] = zero;
    #pragma unroll
    for (int s = 0; s < 8; ++s) {
        bf16x8 a2 = *(const bf16x8*)&sm[w][r15][s * 32 + q * 8];
        #pragma unroll
        for (int t2 = 0; t2 < 2; ++t2)
            c2[t2] = __builtin_amdgcn_mfma_f32_16x16x32_bf16(
                a2, wfpP[(s * 2 + t2) * 64 + lane], c2[t2], 0, 0, 0);
    }
    #pragma unroll
    for (int t2 = 0; t2 < 2; ++t2) {
        int col = t2 * 16 + r15;
        if (col >= LH) continue;
        #pragma unroll
        for (int r = 0; r < 4; ++r) {
            int e2 = eb + q * 4 + r;
            if (e2 < E) {
                int pk = pos[e2];
                a_e_csr[(size_t)pk * LH + col] = c2[t2][r];
            }
        }
    }
}

// ---------------------------------------------------------------------------
__global__ void deg_kernel(const int* __restrict__ dst, int* __restrict__ deg, int E) {
    int e = blockIdx.x * 256 + threadIdx.x;
    if (e < E) atomicAdd(&deg[dst[e]], 1);
}

// K3: self-loop a_e = mean of incoming (contiguous CSR rows)
__global__ void self_ae_kernel(const int* __restrict__ row_ptr,
                               float* __restrict__ a_e_csr, int N, int E) {
    int i = blockIdx.x * 256 + threadIdx.x;
    if (i >= N * LH) return;
    int n = i / LH;
    int j = i % LH;
    int rs = row_ptr[n], re = row_ptr[n + 1];
    float s = 0.f;
    for (int k = rs; k < re; ++k)
        s += a_e_csr[(size_t)k * LH + j];
    a_e_csr[(size_t)(E + n) * LH + j] = s / (float)max(re - rs, 1);
}

// K4 v2: exclusive scan deg -> row_ptr+cursor; shuffle-based
__global__ __launch_bounds__(1024) void scan_kernel(const int* __restrict__ deg,
                                                    int* __restrict__ row_ptr,
                                                    int* __restrict__ cursor, int n) {
    __shared__ int wsum[16];
    __shared__ int carry_s;
    int tid = threadIdx.x;
    int w = tid >> 6, lane = tid & 63;
    if (tid == 0) carry_s = 0;
    __syncthreads();
    for (int base = 0; base < n; base += 1024) {
        int i = base + tid;
        int v = (i < n) ? deg[i] : 0;
        int carry = carry_s;
        int s = v;
        #pragma unroll
        for (int off = 1; off < 64; off <<= 1) {
            int t = __shfl_up(s, off, 64);
            if (lane >= off) s += t;
        }
        if (lane == 63) wsum[w] = s;
        __syncthreads();
        if (w == 0 && lane < 16) {
            int ws = wsum[lane];
            #pragma unroll
            for (int off = 1; off < 16; off <<= 1) {
                int t = __shfl_up(ws, off, 64);
                if (lane >= off) ws += t;
            }
            wsum[lane] = ws;
        }
        __syncthreads();
        int waveoff = (w == 0) ? 0 : wsum[w - 1];
        if (i < n) {
            int ex = carry + waveoff + s - v;
            row_ptr[i] = ex;
            cursor[i] = ex;
        }
        __syncthreads();
        if (tid == 0) carry_s = carry + wsum[15];
        __syncthreads();
    }
    if (tid == 0) row_ptr[n] = carry_s;
}

// K4c: scatter edges into CSR order by dst; emit inverse perm pos[e]
__global__ void scatter_kernel(const int* __restrict__ src, const int* __restrict__ dst,
                               int* __restrict__ cursor, int* __restrict__ csr_src,
                               int* __restrict__ pos, int E) {
    int e = blockIdx.x * 256 + threadIdx.x;
    if (e >= E) return;
    int d = dst[e];
    int pk = atomicAdd(&cursor[d], 1);
    csr_src[pk] = src[e];
    pos[e] = pk;
}

// ---------------------------------------------------------------------------
// MFMA GEMM v2: 64 rows x 128 cols (2 heads) per block — halves hbf re-reads.
// blockIdx.y in {0,1} = head pair. Fused epilogues (a_s/a_d or gate).
__global__ __launch_bounds__(256) void gemm_mfma_kernel(
    const __bf16* __restrict__ hbf, const __bf16* __restrict__ wf,
    __bf16* __restrict__ xhbf, int M,
    const float* __restrict__ att_src, const float* __restrict__ att_dst,
    float* __restrict__ a_s, float* __restrict__ a_d,
    const float* __restrict__ bias, const float* __restrict__ gate_w2,
    const float* __restrict__ gate_b2, float* __restrict__ gate_out) {
    int tid = threadIdx.x;
    int w = tid >> 6, lane = tid & 63;
    int q = lane >> 4, r15 = lane & 15;
    int m0 = blockIdx.x * 64;
    int y2 = blockIdx.y;          // head pair
    int arow = m0 + w * 16 + r15;
    int arowc = min(arow, M - 1);
    const __bf16* ap = hbf + (size_t)arowc * DD + q * 8;
    const bf16x8* wfP = (const bf16x8*)wf;
    f32x4 acc[8];
    #pragma unroll
    for (int g = 0; g < 8; ++g) acc[g] = (f32x4){0.f, 0.f, 0.f, 0.f};
    #pragma unroll
    for (int ks = 0; ks < 8; ++ks) {
        bf16x8 a = *(const bf16x8*)(ap + ks * 32);
        #pragma unroll
        for (int g = 0; g < 8; ++g) {
            int y = y2 * 2 + (g >> 2);   // head
            int t = g & 3;               // subtile within head
            bf16x8 b = wfP[(size_t)(((y * 8 + ks) * 4) + t) * 64 + lane];
            acc[g] = __builtin_amdgcn_mfma_f32_16x16x32_bf16(a, b, acc[g], 0, 0, 0);
        }
    }
    if (xhbf) {
        #pragma unroll
        for (int g = 0; g < 8; ++g) {
            int col = (y2 * 8 + g) * 16 + r15;
            #pragma unroll
            for (int r = 0; r < 4; ++r) {
                int rc = m0 + w * 16 + q * 4 + r;
                if (rc < M) xhbf[(size_t)rc * DD + col] = (__bf16)acc[g][r];
            }
        }
    }
    if (att_src) {
        #pragma unroll
        for (int r = 0; r < 4; ++r) {
            float ps0 = 0.f, pd0 = 0.f, ps1 = 0.f, pd1 = 0.f;
            #pragma unroll
            for (int g = 0; g < 8; ++g) {
                int col = (y2 * 8 + g) * 16 + r15;
                float v = acc[g][r];
                if (g < 4) { ps0 += v * att_src[col]; pd0 += v * att_dst[col]; }
                else       { ps1 += v * att_src[col]; pd1 += v * att_dst[col]; }
            }
            #pragma unroll
            for (int mask = 1; mask < 16; mask <<= 1) {
                ps0 += __shfl_xor(ps0, mask, 64);
                pd0 += __shfl_xor(pd0, mask, 64);
                ps1 += __shfl_xor(ps1, mask, 64);
                pd1 += __shfl_xor(pd1, mask, 64);
            }
            int rc = m0 + w * 16 + q * 4 + r;
            if (r15 == 0 && rc < M) {
                a_s[rc * HH + y2 * 2 + 0] = ps0;
                a_d[rc * HH + y2 * 2 + 0] = pd0;
                a_s[rc * HH + y2 * 2 + 1] = ps1;
                a_d[rc * HH + y2 * 2 + 1] = pd1;
            }
        }
    }
    if (gate_w2) {
        #pragma unroll
        for (int r = 0; r < 4; ++r) {
            float pg = 0.f;
            #pragma unroll
            for (int g = 0; g < 8; ++g) {
                int col = (y2 * 8 + g) * 16 + r15;
                pg += fmaxf(acc[g][r] + bias[col], 0.f) * gate_w2[col];
            }
            #pragma unroll
            for (int mask = 1; mask < 16; mask <<= 1) pg += __shfl_xor(pg, mask, 64);
            int rc = m0 + w * 16 + q * 4 + r;
            if (r15 == 0 && rc < M) {
                float add = pg + (y2 == 0 ? gate_b2[0] : 0.f);
                atomicAdd(&gate_out[rc], add);
            }
        }
    }
}

// ---------------------------------------------------------------------------
// K6 v7: WAVE-PER-NODE; CSR a_e; lsrc LDS cache; pass-3 unroll x2.
__global__ __launch_bounds__(256) void gat_message7_kernel(
    const __bf16* __restrict__ xhbf, const float* __restrict__ a_s,
    const float* __restrict__ a_d, const float* __restrict__ a_e,  // +l*4; [k][20]
    const int* __restrict__ row_ptr, const int* __restrict__ csr_src,
    const float* __restrict__ gat_b,
    const float* __restrict__ ln_g, const float* __restrict__ ln_b,
    float* __restrict__ h, __bf16* __restrict__ hbf, int N, int E) {
    __shared__ float lws[4][WCAP * 4];   // 12 KB
    __shared__ int lsrc[4][WCAP];        // 3 KB
    int tid = threadIdx.x;
    int w = tid >> 6, lane = tid & 63;
    int n = blockIdx.x * 4 + w;
    if (n >= N) return;
    int hh = lane >> 4, j = lane & 15;
    int rs = row_ptr[n], re = row_ptr[n + 1];
    int deg = re - rs;
    float adn = a_d[n * HH + hh];
    float al_self = lrelu(a_s[n * HH + hh] + adn + a_e[(size_t)(E + n) * LH + hh]);
    float m = al_self, den = 0.f;
    for (int k = rs + j; k < re; k += 16) {
        int kk = k - rs;
        int s = csr_src[k];
        float a = lrelu(a_s[s * HH + hh] + adn + a_e[(size_t)k * LH + hh]);
        if (kk < WCAP) {
            lws[w][kk * 4 + hh] = a;
            if (hh == 0) lsrc[w][kk] = s;
        }
        float mn = fmaxf(m, a);
        den = den * __expf(m - mn) + __expf(a - mn);
        m = mn;
    }
    #pragma unroll
    for (int off = 1; off < 16; off <<= 1) {
        float m2 = __shfl_xor(m, off, 64);
        float d2 = __shfl_xor(den, off, 64);
        float mn = fmaxf(m, m2);
        den = den * __expf(m - mn) + d2 * __expf(m2 - mn);
        m = mn;
    }
    den += __expf(al_self - m);
    float inv_den = 1.0f / den;
    int cap = min(deg, WCAP);
    for (int kk = j; kk < cap; kk += 16)
        lws[w][kk * 4 + hh] = __expf(lws[w][kk * 4 + hh] - m) * inv_den;
    float wself = __expf(al_self - m) * inv_den;
    bf16x4 xsb = *((const bf16x4*)(xhbf + (size_t)n * DD) + lane);
    float4 acc;
    acc.x = wself * (float)xsb[0]; acc.y = wself * (float)xsb[1];
    acc.z = wself * (float)xsb[2]; acc.w = wself * (float)xsb[3];
    int k = rs;
    for (; k + 1 < re; k += 2) {
        int kk0 = k - rs, kk1 = kk0 + 1;
        int s0, s1_;
        float w0, w1;
        if (kk1 < WCAP) {
            s0 = lsrc[w][kk0]; s1_ = lsrc[w][kk1];
            w0 = lws[w][kk0 * 4 + hh]; w1 = lws[w][kk1 * 4 + hh];
        } else {
            s0 = csr_src[k]; s1_ = csr_src[k + 1];
            w0 = (kk0 < WCAP) ? lws[w][kk0 * 4 + hh]
               : __expf(lrelu(a_s[s0 * HH + hh] + adn + a_e[(size_t)k * LH + hh]) - m) * inv_den;
            w1 = __expf(lrelu(a_s[s1_ * HH + hh] + adn + a_e[(size_t)(k + 1) * LH + hh]) - m) * inv_den;
        }
        bf16x4 x0 = *((const bf16x4*)(xhbf + (size_t)s0 * DD) + lane);
        bf16x4 x1 = *((const bf16x4*)(xhbf + (size_t)s1_ * DD) + lane);
        acc.x += w0 * (float)x0[0] + w1 * (float)x1[0];
        acc.y += w0 * (float)x0[1] + w1 * (float)x1[1];
        acc.z += w0 * (float)x0[2] + w1 * (float)x1[2];
        acc.w += w0 * (float)x0[3] + w1 * (float)x1[3];
    }
    if (k < re) {
        int kk0 = k - rs;
        int s0;
        float w0;
        if (kk0 < WCAP) { s0 = lsrc[w][kk0]; w0 = lws[w][kk0 * 4 + hh]; }
        else {
            s0 = csr_src[k];
            w0 = __expf(lrelu(a_s[s0 * HH + hh] + adn + a_e[(size_t)k * LH + hh]) - m) * inv_den;
        }
        bf16x4 x0 = *((const bf16x4*)(xhbf + (size_t)s0 * DD) + lane);
        acc.x += w0 * (float)x0[0]; acc.y += w0 * (float)x0[1];
        acc.z += w0 * (float)x0[2]; acc.w += w0 * (float)x0[3];
    }
    float4 gb = *((const float4*)gat_b + lane);
    float4 val;
    val.x = acc.x + gb.x; val.y = acc.y + gb.y;
    val.z = acc.z + gb.z; val.w = acc.w + gb.w;
    float s1 = val.x + val.y + val.z + val.w;
    float s2 = val.x * val.x + val.y * val.y + val.z * val.z + val.w * val.w;
    #pragma unroll
    for (int off = 1; off < 64; off <<= 1) {
        s1 += __shfl_xor(s1, off, 64);
        s2 += __shfl_xor(s2, off, 64);
    }
    float mu = s1 * (1.0f / DD);
    float var = s2 * (1.0f / DD) - mu * mu;
    float rstd = rsqrtf(var + 1e-5f);
    float4 lg = *((const float4*)ln_g + lane);
    float4 lb = *((const float4*)ln_b + lane);
    float4 nv;
    nv.x = fmaxf((val.x - mu) * rstd * lg.x + lb.x, 0.f);
    nv.y = fmaxf((val.y - mu) * rstd * lg.y + lb.y, 0.f);
    nv.z = fmaxf((val.z - mu) * rstd * lg.z + lb.z, 0.f);
    nv.w = fmaxf((val.w - mu) * rstd * lg.w + lb.w, 0.f);
    float4* hp = (float4*)(h + (size_t)n * DD) + lane;
    float4 hv = *hp;
    hv.x += nv.x; hv.y += nv.y; hv.z += nv.z; hv.w += nv.w;
    *hp = hv;
    bf16x4 hb;
    hb[0] = (__bf16)hv.x; hb[1] = (__bf16)hv.y;
    hb[2] = (__bf16)hv.z; hb[3] = (__bf16)hv.w;
    *((bf16x4*)(hbf + (size_t)n * DD) + lane) = hb;
}

// ---------------------------------------------------------------------------
// K7a: per-graph gate max + denom; segment bounds via inline binary search.
__global__ __launch_bounds__(256) void gseg_kernel(
    const float* __restrict__ gate, const int* __restrict__ batch,
    float* __restrict__ gmax, float* __restrict__ gden, int N) {
    int b = blockIdx.x;
    int tid = threadIdx.x;
    __shared__ int bounds[2];
    if (tid < 2) {
        int target = b + tid;
        int lo = 0, hi = N;
        while (lo < hi) {
            int mid = (lo + hi) >> 1;
            if (batch[mid] < target) lo = mid + 1; else hi = mid;
        }
        bounds[tid] = lo;
    }
    __syncthreads();
    int s0 = bounds[0], s1 = bounds[1];
    __shared__ float red[256];
    float m = -1e30f;
    for (int i = s0 + tid; i < s1; i += 256) m = fmaxf(m, gate[i]);
    red[tid] = m;
    __syncthreads();
    for (int off = 128; off; off >>= 1) {
        if (tid < off) red[tid] = fmaxf(red[tid], red[tid + off]);
        __syncthreads();
    }
    float gm = red[0];
    __syncthreads();
    float s = 0.f;
    for (int i = s0 + tid; i < s1; i += 256) s += __expf(gate[i] - gm);
    red[tid] = s;
    __syncthreads();
    for (int off = 128; off; off >>= 1) {
        if (tid < off) red[tid] += red[tid + off];
        __syncthreads();
    }
    if (tid == 0) {
        gmax[b] = gm;
        gden[b] = red[0];
    }
}

// K7d: pooled embedding; softmax weight computed inline.
#define POOL_CHUNK 32
__global__ __launch_bounds__(256) void pool_scatter_kernel(
    const float* __restrict__ h, const float* __restrict__ gate,
    const float* __restrict__ gmax, const float* __restrict__ gden,
    const int* __restrict__ batch, float* __restrict__ g_embed, int N) {
    int i0 = blockIdx.x * POOL_CHUNK;
    int d = threadIdx.x;
    int iend = min(i0 + POOL_CHUNK, N);
    float acc = 0.f;
    int cur = batch[i0];
    for (int i = i0; i < iend; ++i) {
        int b = batch[i];
        if (b != cur) {
            atomicAdd(&g_embed[cur * DD + d], acc);
            acc = 0.f;
            cur = b;
        }
        float wgt = __expf(gate[i] - gmax[b]) / gden[b];
        acc += wgt * h[(size_t)i * DD + d];
    }
    atomicAdd(&g_embed[cur * DD + d], acc);
}

__global__ __launch_bounds__(256) void readout_kernel(
    const float* __restrict__ g_embed, const float* __restrict__ w1,
    const float* __restrict__ b1, const float* __restrict__ w2,
    const float* __restrict__ b2, float* __restrict__ out) {
    int b = blockIdx.x;
    int tid = threadIdx.x;
    __shared__ float gvec[256];
    __shared__ float hid[256];
    gvec[tid] = g_embed[b * DD + tid];
    __syncthreads();
    float hv = b1[tid];
    for (int k = 0; k < DD; ++k) hv += gvec[k] * w1[k * DD + tid];
    hid[tid] = fmaxf(hv, 0.f);
    __syncthreads();
    float o = b2[tid];
    for (int t = 0; t < DD; ++t) o += hid[t] * w2[t * DD + tid];
    out[b * DD + tid] = o;
}

// ---------------------------------------------------------------------------
extern "C" void kernel_launch(void* const* d_in, const int* in_sizes, int n_in,
                              void* d_out, int out_size, void* d_ws, size_t ws_size,
                              hipStream_t stream) {
    const float* x        = (const float*)d_in[0];
    const float* edge_attr= (const float*)d_in[1];
    const int*   edge_idx = (const int*)d_in[2];
    const int*   batch    = (const int*)d_in[3];
    const float* enc_w    = (const float*)d_in[4];
    const float* enc_b    = (const float*)d_in[5];
    const float* eenc_w   = (const float*)d_in[6];
    const float* eenc_b   = (const float*)d_in[7];
    const float* gat_w    = (const float*)d_in[8];
    const float* att_src  = (const float*)d_in[9];
    const float* att_dst  = (const float*)d_in[10];
    const float* att_edge = (const float*)d_in[11];
    const float* gat_ew   = (const float*)d_in[12];
    const float* gat_b    = (const float*)d_in[13];
    const float* ln_g     = (const float*)d_in[14];
    const float* ln_b     = (const float*)d_in[15];
    const float* gate_w1  = (const float*)d_in[16];
    const float* gate_b1  = (const float*)d_in[17];
    const float* gate_w2  = (const float*)d_in[18];
    const float* gate_b2  = (const float*)d_in[19];
    const float* ro_w1    = (const float*)d_in[20];
    const float* ro_b1    = (const float*)d_in[21];
    const float* ro_w2    = (const float*)d_in[22];
    const float* ro_b2    = (const float*)d_in[23];
    float* out = (float*)d_out;

    const int N = in_sizes[0] / 42;       // 10000
    const int E = in_sizes[1] / 12;       // 160000
    const int B = out_size / DD;          // 16

    // workspace carve-up
    char* p = (char*)d_ws;
    auto alloc = [&](size_t bytes) {
        char* r = p;
        p += (bytes + 255) & ~(size_t)255;
        return (void*)r;
    };
    float*  h       = (float*)alloc((size_t)N * DD * 4);
    __bf16* hbf     = (__bf16*)alloc((size_t)N * DD * 2);
    __bf16* xhbf    = (__bf16*)alloc((size_t)N * DD * 2);
    float*  a_s     = (float*)alloc((size_t)N * HH * 4);
    float*  a_d     = (float*)alloc((size_t)N * HH * 4);
    float*  a_e_csr = (float*)alloc((size_t)(E + N) * LH * 4);
    float*  wproj   = (float*)alloc((size_t)DD * LH * 4);
    __bf16* wfe     = (__bf16*)alloc((size_t)16 * 64 * 8 * 2);
    __bf16* wfp     = (__bf16*)alloc((size_t)16 * 64 * 8 * 2);
    __bf16* wf      = (__bf16*)alloc((size_t)6 * DD * DD * 2);
    float*  gate    = (float*)alloc((size_t)N * 4);
    float*  g_embed = (float*)alloc((size_t)B * DD * 4);
    float*  gmax    = (float*)alloc((size_t)B * 4);
    float*  gden    = (float*)alloc((size_t)B * 4);
    int* deg        = (int*)alloc((size_t)N * 4);
    int* row_ptr    = (int*)alloc((size_t)(N + 1) * 4);
    int* cursor     = (int*)alloc((size_t)N * 4);
    int* csr_src    = (int*)alloc((size_t)E * 4);
    int* pos        = (int*)alloc((size_t)E * 4);

    const int* src_arr = edge_idx;
    const int* dst_arr = edge_idx + E;

    hipMemsetAsync(deg, 0, (size_t)N * 4, stream);
    hipMemsetAsync(g_embed, 0, (size_t)B * DD * 4, stream);
    hipMemsetAsync(gate, 0, (size_t)N * 4, stream);

    edge_setup_kernel<<<1, 256, 0, stream>>>(gat_ew, att_edge, eenc_w, eenc_b,
                                             wproj, wfe, wfp);
    wswizzle_kernel<<<192, 256, 0, stream>>>(gat_w, gate_w1, wf);
    encoder_kernel<<<N, 256, 0, stream>>>(x, enc_w, enc_b, h, hbf, N);
    deg_kernel<<<(E + 255) / 256, 256, 0, stream>>>(dst_arr, deg, E);
    scan_kernel<<<1, 1024, 0, stream>>>(deg, row_ptr, cursor, N);
    scatter_kernel<<<(E + 255) / 256, 256, 0, stream>>>(
        src_arr, dst_arr, cursor, csr_src, pos, E);
    edge_mfma_kernel<<<(E + 63) / 64, 256, 0, stream>>>(
        edge_attr, wfe, wfp, pos, a_e_csr, E);
    self_ae_kernel<<<(N * LH + 255) / 256, 256, 0, stream>>>(
        row_ptr, a_e_csr, N, E);

    dim3 ggrid((N + 63) / 64, 2);
    for (int l = 0; l < LL; ++l) {
        gemm_mfma_kernel<<<ggrid, 256, 0, stream>>>(
            hbf, wf + (size_t)l * DD * DD, xhbf, N,
            att_src + l * DD, att_dst + l * DD, a_s, a_d,
            nullptr, nullptr, nullptr, nullptr);
        gat_message7_kernel<<<(N + 3) / 4, 256, 0, stream>>>(
            xhbf, a_s, a_d, a_e_csr + l * HH, row_ptr, csr_src,
            gat_b + l * DD, ln_g + l * DD, ln_b + l * DD, h, hbf, N, E);
    }

    // pooling gate: gate[n] = relu(h@gate_w1+b1) . gate_w2 + b2, fused MFMA
    gemm_mfma_kernel<<<ggrid, 256, 0, stream>>>(
        hbf, wf + (size_t)5 * DD * DD, nullptr, N,
        nullptr, nullptr, nullptr, nullptr,
        gate_b1, gate_w2, gate_b2, gate);
    gseg_kernel<<<B, 256, 0, stream>>>(gate, batch, gmax, gden, N);
    pool_scatter_kernel<<<(N + POOL_CHUNK - 1) / POOL_CHUNK, 256, 0, stream>>>(
        h, gate, gmax, gden, batch, g_embed, N);
    readout_kernel<<<B, 256, 0, stream>>>(g_embed, ro_w1, ro_b1, ro_w2, ro_b2, out);
}

// Round 16
// 428.672 us; speedup vs baseline: 1.0682x; 1.0682x over previous
//
#include <hip/hip_runtime.h>
#include <math.h>

// Problem constants (fixed-shape problem)
#define DD 256
#define HH 4
#define CC 64
#define LL 5
#define NEG_SLOPE 0.2f
#define LH 20   // L*H
#define WCAP 192  // per-wave LDS softmax-weight cache

typedef __bf16 bf16x8 __attribute__((ext_vector_type(8)));
typedef __bf16 bf16x4 __attribute__((ext_vector_type(4)));
typedef float f32x4 __attribute__((ext_vector_type(4)));

static __device__ __forceinline__ float lrelu(float x) {
    return x > 0.0f ? x : NEG_SLOPE * x;
}

// ---------------------------------------------------------------------------
// K0: wproj[k][l*4+h] = sum_c gat_ew[l][k][h*64+c] * att_edge[l][h][c]
// (5 blocks — one per layer; single-block version was a 65 µs serial bottleneck)
__global__ __launch_bounds__(256) void wproj_kernel(
    const float* __restrict__ gat_ew, const float* __restrict__ att_edge,
    float* __restrict__ wproj) {
    int l = blockIdx.x;
    int k = threadIdx.x;
    const float* W = gat_ew + (size_t)l * DD * DD;
    const float* att = att_edge + l * DD;
    for (int hh = 0; hh < HH; ++hh) {
        float s = 0.f;
        #pragma unroll
        for (int c = 0; c < CC; ++c)
            s += W[k * DD + hh * CC + c] * att[hh * CC + c];
        wproj[k * LH + l * HH + hh] = s;
    }
}

// K0b: pack edge-encoder + wproj weights into MFMA B-fragment order (bf16).
__global__ __launch_bounds__(256) void pack_edge_frags_kernel(
    const float* __restrict__ eenc_w, const float* __restrict__ eenc_b,
    const float* __restrict__ wproj, __bf16* __restrict__ wfe,
    __bf16* __restrict__ wfp) {
    int tid = threadIdx.x;
    for (int idx = tid; idx < 16 * 64; idx += 256) {
        int t = idx >> 6, lane = idx & 63;
        int q = lane >> 4, r15 = lane & 15;
        int col = t * 16 + r15;
        #pragma unroll
        for (int j = 0; j < 8; ++j) {
            int k = q * 8 + j;
            float v = (k < 12) ? eenc_w[k * 256 + col]
                               : (k == 12 ? eenc_b[col] : 0.f);
            wfe[(size_t)idx * 8 + j] = (__bf16)v;
        }
    }
    for (int idx = tid; idx < 16 * 64; idx += 256) {
        int sidx = idx >> 6, lane = idx & 63;
        int s = sidx >> 1, t2 = sidx & 1;
        int q = lane >> 4, r15 = lane & 15;
        int col = t2 * 16 + r15;
        #pragma unroll
        for (int j = 0; j < 8; ++j) {
            int k = s * 32 + q * 8 + j;
            float v = (col < LH) ? wproj[k * LH + col] : 0.f;
            wfp[(size_t)idx * 8 + j] = (__bf16)v;
        }
    }
}

// ---------------------------------------------------------------------------
// K0c: swizzle GEMM weights into MFMA B-fragment order, bf16.
__global__ __launch_bounds__(256) void wswizzle_kernel(
    const float* __restrict__ gat_w, const float* __restrict__ gate_w1,
    __bf16* __restrict__ wf) {
    int b = blockIdx.x;           // l*32 + y*8 + ks
    int l = b >> 5;
    int rem = b & 31;
    int y = rem >> 3, ks = rem & 7;
    int tid = threadIdx.x;
    int t = tid >> 6, lane = tid & 63;
    int q = lane >> 4, r15 = lane & 15;
    const float* W = (l < 5) ? (gat_w + (size_t)l * DD * DD) : gate_w1;
    size_t obase = (((size_t)b * 4 + t) * 64 + lane) * 8;
    int kbase = ks * 32 + q * 8;
    int col = y * 64 + t * 16 + r15;
    #pragma unroll
    for (int j = 0; j < 8; ++j)
        wf[obase + j] = (__bf16)W[(size_t)(kbase + j) * DD + col];
}

// ---------------------------------------------------------------------------
// K1: node encoder h = relu(x @ enc_w + enc_b); also writes bf16 shadow
__global__ __launch_bounds__(256) void encoder_kernel(
    const float* __restrict__ x, const float* __restrict__ enc_w,
    const float* __restrict__ enc_b, float* __restrict__ h,
    __bf16* __restrict__ hbf, int N) {
    int n = blockIdx.x;
    int tid = threadIdx.x;
    __shared__ float xs[42];
    if (tid < 42) xs[tid] = x[(size_t)n * 42 + tid];
    __syncthreads();
    float acc = enc_b[tid];
    #pragma unroll
    for (int f = 0; f < 42; ++f) acc += xs[f] * enc_w[f * DD + tid];
    float v = fmaxf(acc, 0.f);
    h[(size_t)n * DD + tid] = v;
    hbf[(size_t)n * DD + tid] = (__bf16)v;
}

// ---------------------------------------------------------------------------
// K2 v6: edge_pre on matrix cores; output in CSR order via pos[e].
__global__ __launch_bounds__(256) void edge_mfma_kernel(
    const float* __restrict__ edge_attr, const __bf16* __restrict__ wfe,
    const __bf16* __restrict__ wfp, const int* __restrict__ pos,
    float* __restrict__ a_e_csr, int E) {
    __shared__ __bf16 sm[4][16][264];   // 33 KB
    int tid = threadIdx.x;
    int w = tid >> 6, lane = tid & 63;
    int q = lane >> 4, r15 = lane & 15;
    int eb = blockIdx.x * 64 + w * 16;
    int e = eb + r15;
    int ec = min(e, E - 1);
    bf16x8 a1;
    #pragma unroll
    for (int j = 0; j < 8; ++j) a1[j] = (__bf16)0.f;
    if (q == 0) {
        const float4* p = (const float4*)(edge_attr + (size_t)ec * 12);
        float4 p0 = p[0], p1 = p[1];
        a1[0] = (__bf16)p0.x; a1[1] = (__bf16)p0.y; a1[2] = (__bf16)p0.z; a1[3] = (__bf16)p0.w;
        a1[4] = (__bf16)p1.x; a1[5] = (__bf16)p1.y; a1[6] = (__bf16)p1.z; a1[7] = (__bf16)p1.w;
    } else if (q == 1) {
        float4 p2 = *(const float4*)(edge_attr + (size_t)ec * 12 + 8);
        a1[0] = (__bf16)p2.x; a1[1] = (__bf16)p2.y; a1[2] = (__bf16)p2.z; a1[3] = (__bf16)p2.w;
        a1[4] = (__bf16)1.0f;  // k = 12: bias row
    }
    const bf16x8* wfeP = (const bf16x8*)wfe;
    f32x4 zero = (f32x4){0.f, 0.f, 0.f, 0.f};
    #pragma unroll
    for (int t = 0; t < 16; ++t) {
        bf16x8 bfr = wfeP[t * 64 + lane];
        f32x4 c = __builtin_amdgcn_mfma_f32_16x16x32_bf16(a1, bfr, zero, 0, 0, 0);
        int col = t * 16 + r15;
        #pragma unroll
        for (int r = 0; r < 4; ++r)
            sm[w][q * 4 + r][col] = (__bf16)fmaxf(c[r], 0.f);
    }
    const bf16x8* wfpP = (const bf16x8*)wfp;
    f32x4 c2[2];
    c2[0] = zero; c2[1] = zero;
    #pragma unroll
    for (int s = 0; s < 8; ++s) {
        bf16x8 a2 = *(const bf16x8*)&sm[w][r15][s * 32 + q * 8];
        #pragma unroll
        for (int t2 = 0; t2 < 2; ++t2)
            c2[t2] = __builtin_amdgcn_mfma_f32_16x16x32_bf16(
                a2, wfpP[(s * 2 + t2) * 64 + lane], c2[t2], 0, 0, 0);
    }
    #pragma unroll
    for (int t2 = 0; t2 < 2; ++t2) {
        int col = t2 * 16 + r15;
        if (col >= LH) continue;
        #pragma unroll
        for (int r = 0; r < 4; ++r) {
            int e2 = eb + q * 4 + r;
            if (e2 < E) {
                int pk = pos[e2];
                a_e_csr[(size_t)pk * LH + col] = c2[t2][r];
            }
        }
    }
}

// ---------------------------------------------------------------------------
__global__ void deg_kernel(const int* __restrict__ dst, int* __restrict__ deg, int E) {
    int e = blockIdx.x * 256 + threadIdx.x;
    if (e < E) atomicAdd(&deg[dst[e]], 1);
}

// K3: self-loop a_e = mean of incoming (contiguous CSR rows)
__global__ void self_ae_kernel(const int* __restrict__ row_ptr,
                               float* __restrict__ a_e_csr, int N, int E) {
    int i = blockIdx.x * 256 + threadIdx.x;
    if (i >= N * LH) return;
    int n = i / LH;
    int j = i % LH;
    int rs = row_ptr[n], re = row_ptr[n + 1];
    float s = 0.f;
    for (int k = rs; k < re; ++k)
        s += a_e_csr[(size_t)k * LH + j];
    a_e_csr[(size_t)(E + n) * LH + j] = s / (float)max(re - rs, 1);
}

// K4 v2: exclusive scan deg -> row_ptr+cursor; shuffle-based
__global__ __launch_bounds__(1024) void scan_kernel(const int* __restrict__ deg,
                                                    int* __restrict__ row_ptr,
                                                    int* __restrict__ cursor, int n) {
    __shared__ int wsum[16];
    __shared__ int carry_s;
    int tid = threadIdx.x;
    int w = tid >> 6, lane = tid & 63;
    if (tid == 0) carry_s = 0;
    __syncthreads();
    for (int base = 0; base < n; base += 1024) {
        int i = base + tid;
        int v = (i < n) ? deg[i] : 0;
        int carry = carry_s;
        int s = v;
        #pragma unroll
        for (int off = 1; off < 64; off <<= 1) {
            int t = __shfl_up(s, off, 64);
            if (lane >= off) s += t;
        }
        if (lane == 63) wsum[w] = s;
        __syncthreads();
        if (w == 0 && lane < 16) {
            int ws = wsum[lane];
            #pragma unroll
            for (int off = 1; off < 16; off <<= 1) {
                int t = __shfl_up(ws, off, 64);
                if (lane >= off) ws += t;
            }
            wsum[lane] = ws;
        }
        __syncthreads();
        int waveoff = (w == 0) ? 0 : wsum[w - 1];
        if (i < n) {
            int ex = carry + waveoff + s - v;
            row_ptr[i] = ex;
            cursor[i] = ex;
        }
        __syncthreads();
        if (tid == 0) carry_s = carry + wsum[15];
        __syncthreads();
    }
    if (tid == 0) row_ptr[n] = carry_s;
}

// K4c: scatter edges into CSR order by dst; emit inverse perm pos[e]
__global__ void scatter_kernel(const int* __restrict__ src, const int* __restrict__ dst,
                               int* __restrict__ cursor, int* __restrict__ csr_src,
                               int* __restrict__ pos, int E) {
    int e = blockIdx.x * 256 + threadIdx.x;
    if (e >= E) return;
    int d = dst[e];
    int pk = atomicAdd(&cursor[d], 1);
    csr_src[pk] = src[e];
    pos[e] = pk;
}

// ---------------------------------------------------------------------------
// MFMA GEMM v2: 64 rows x 128 cols (2 heads) per block — halves hbf re-reads.
__global__ __launch_bounds__(256) void gemm_mfma_kernel(
    const __bf16* __restrict__ hbf, const __bf16* __restrict__ wf,
    __bf16* __restrict__ xhbf, int M,
    const float* __restrict__ att_src, const float* __restrict__ att_dst,
    float* __restrict__ a_s, float* __restrict__ a_d,
    const float* __restrict__ bias, const float* __restrict__ gate_w2,
    const float* __restrict__ gate_b2, float* __restrict__ gate_out) {
    int tid = threadIdx.x;
    int w = tid >> 6, lane = tid & 63;
    int q = lane >> 4, r15 = lane & 15;
    int m0 = blockIdx.x * 64;
    int y2 = blockIdx.y;          // head pair
    int arow = m0 + w * 16 + r15;
    int arowc = min(arow, M - 1);
    const __bf16* ap = hbf + (size_t)arowc * DD + q * 8;
    const bf16x8* wfP = (const bf16x8*)wf;
    f32x4 acc[8];
    #pragma unroll
    for (int g = 0; g < 8; ++g) acc[g] = (f32x4){0.f, 0.f, 0.f, 0.f};
    #pragma unroll
    for (int ks = 0; ks < 8; ++ks) {
        bf16x8 a = *(const bf16x8*)(ap + ks * 32);
        #pragma unroll
        for (int g = 0; g < 8; ++g) {
            int y = y2 * 2 + (g >> 2);   // head
            int t = g & 3;               // subtile within head
            bf16x8 b = wfP[(size_t)(((y * 8 + ks) * 4) + t) * 64 + lane];
            acc[g] = __builtin_amdgcn_mfma_f32_16x16x32_bf16(a, b, acc[g], 0, 0, 0);
        }
    }
    if (xhbf) {
        #pragma unroll
        for (int g = 0; g < 8; ++g) {
            int col = (y2 * 8 + g) * 16 + r15;
            #pragma unroll
            for (int r = 0; r < 4; ++r) {
                int rc = m0 + w * 16 + q * 4 + r;
                if (rc < M) xhbf[(size_t)rc * DD + col] = (__bf16)acc[g][r];
            }
        }
    }
    if (att_src) {
        #pragma unroll
        for (int r = 0; r < 4; ++r) {
            float ps0 = 0.f, pd0 = 0.f, ps1 = 0.f, pd1 = 0.f;
            #pragma unroll
            for (int g = 0; g < 8; ++g) {
                int col = (y2 * 8 + g) * 16 + r15;
                float v = acc[g][r];
                if (g < 4) { ps0 += v * att_src[col]; pd0 += v * att_dst[col]; }
                else       { ps1 += v * att_src[col]; pd1 += v * att_dst[col]; }
            }
            #pragma unroll
            for (int mask = 1; mask < 16; mask <<= 1) {
                ps0 += __shfl_xor(ps0, mask, 64);
                pd0 += __shfl_xor(pd0, mask, 64);
                ps1 += __shfl_xor(ps1, mask, 64);
                pd1 += __shfl_xor(pd1, mask, 64);
            }
            int rc = m0 + w * 16 + q * 4 + r;
            if (r15 == 0 && rc < M) {
                a_s[rc * HH + y2 * 2 + 0] = ps0;
                a_d[rc * HH + y2 * 2 + 0] = pd0;
                a_s[rc * HH + y2 * 2 + 1] = ps1;
                a_d[rc * HH + y2 * 2 + 1] = pd1;
            }
        }
    }
    if (gate_w2) {
        #pragma unroll
        for (int r = 0; r < 4; ++r) {
            float pg = 0.f;
            #pragma unroll
            for (int g = 0; g < 8; ++g) {
                int col = (y2 * 8 + g) * 16 + r15;
                pg += fmaxf(acc[g][r] + bias[col], 0.f) * gate_w2[col];
            }
            #pragma unroll
            for (int mask = 1; mask < 16; mask <<= 1) pg += __shfl_xor(pg, mask, 64);
            int rc = m0 + w * 16 + q * 4 + r;
            if (r15 == 0 && rc < M) {
                float add = pg + (y2 == 0 ? gate_b2[0] : 0.f);
                atomicAdd(&gate_out[rc], add);
            }
        }
    }
}

// ---------------------------------------------------------------------------
// K6 v7: WAVE-PER-NODE; CSR a_e; lsrc LDS cache; pass-3 unroll x2.
__global__ __launch_bounds__(256) void gat_message7_kernel(
    const __bf16* __restrict__ xhbf, const float* __restrict__ a_s,
    const float* __restrict__ a_d, const float* __restrict__ a_e,  // +l*4; [k][20]
    const int* __restrict__ row_ptr, const int* __restrict__ csr_src,
    const float* __restrict__ gat_b,
    const float* __restrict__ ln_g, const float* __restrict__ ln_b,
    float* __restrict__ h, __bf16* __restrict__ hbf, int N, int E) {
    __shared__ float lws[4][WCAP * 4];   // 12 KB
    __shared__ int lsrc[4][WCAP];        // 3 KB
    int tid = threadIdx.x;
    int w = tid >> 6, lane = tid & 63;
    int n = blockIdx.x * 4 + w;
    if (n >= N) return;
    int hh = lane >> 4, j = lane & 15;
    int rs = row_ptr[n], re = row_ptr[n + 1];
    int deg = re - rs;
    float adn = a_d[n * HH + hh];
    float al_self = lrelu(a_s[n * HH + hh] + adn + a_e[(size_t)(E + n) * LH + hh]);
    float m = al_self, den = 0.f;
    for (int k = rs + j; k < re; k += 16) {
        int kk = k - rs;
        int s = csr_src[k];
        float a = lrelu(a_s[s * HH + hh] + adn + a_e[(size_t)k * LH + hh]);
        if (kk < WCAP) {
            lws[w][kk * 4 + hh] = a;
            if (hh == 0) lsrc[w][kk] = s;
        }
        float mn = fmaxf(m, a);
        den = den * __expf(m - mn) + __expf(a - mn);
        m = mn;
    }
    #pragma unroll
    for (int off = 1; off < 16; off <<= 1) {
        float m2 = __shfl_xor(m, off, 64);
        float d2 = __shfl_xor(den, off, 64);
        float mn = fmaxf(m, m2);
        den = den * __expf(m - mn) + d2 * __expf(m2 - mn);
        m = mn;
    }
    den += __expf(al_self - m);
    float inv_den = 1.0f / den;
    int cap = min(deg, WCAP);
    for (int kk = j; kk < cap; kk += 16)
        lws[w][kk * 4 + hh] = __expf(lws[w][kk * 4 + hh] - m) * inv_den;
    float wself = __expf(al_self - m) * inv_den;
    bf16x4 xsb = *((const bf16x4*)(xhbf + (size_t)n * DD) + lane);
    float4 acc;
    acc.x = wself * (float)xsb[0]; acc.y = wself * (float)xsb[1];
    acc.z = wself * (float)xsb[2]; acc.w = wself * (float)xsb[3];
    int k = rs;
    for (; k + 1 < re; k += 2) {
        int kk0 = k - rs, kk1 = kk0 + 1;
        int s0, s1_;
        float w0, w1;
        if (kk1 < WCAP) {
            s0 = lsrc[w][kk0]; s1_ = lsrc[w][kk1];
            w0 = lws[w][kk0 * 4 + hh]; w1 = lws[w][kk1 * 4 + hh];
        } else {
            s0 = csr_src[k]; s1_ = csr_src[k + 1];
            w0 = (kk0 < WCAP) ? lws[w][kk0 * 4 + hh]
               : __expf(lrelu(a_s[s0 * HH + hh] + adn + a_e[(size_t)k * LH + hh]) - m) * inv_den;
            w1 = __expf(lrelu(a_s[s1_ * HH + hh] + adn + a_e[(size_t)(k + 1) * LH + hh]) - m) * inv_den;
        }
        bf16x4 x0 = *((const bf16x4*)(xhbf + (size_t)s0 * DD) + lane);
        bf16x4 x1 = *((const bf16x4*)(xhbf + (size_t)s1_ * DD) + lane);
        acc.x += w0 * (float)x0[0] + w1 * (float)x1[0];
        acc.y += w0 * (float)x0[1] + w1 * (float)x1[1];
        acc.z += w0 * (float)x0[2] + w1 * (float)x1[2];
        acc.w += w0 * (float)x0[3] + w1 * (float)x1[3];
    }
    if (k < re) {
        int kk0 = k - rs;
        int s0;
        float w0;
        if (kk0 < WCAP) { s0 = lsrc[w][kk0]; w0 = lws[w][kk0 * 4 + hh]; }
        else {
            s0 = csr_src[k];
            w0 = __expf(lrelu(a_s[s0 * HH + hh] + adn + a_e[(size_t)k * LH + hh]) - m) * inv_den;
        }
        bf16x4 x0 = *((const bf16x4*)(xhbf + (size_t)s0 * DD) + lane);
        acc.x += w0 * (float)x0[0]; acc.y += w0 * (float)x0[1];
        acc.z += w0 * (float)x0[2]; acc.w += w0 * (float)x0[3];
    }
    float4 gb = *((const float4*)gat_b + lane);
    float4 val;
    val.x = acc.x + gb.x; val.y = acc.y + gb.y;
    val.z = acc.z + gb.z; val.w = acc.w + gb.w;
    float s1 = val.x + val.y + val.z + val.w;
    float s2 = val.x * val.x + val.y * val.y + val.z * val.z + val.w * val.w;
    #pragma unroll
    for (int off = 1; off < 64; off <<= 1) {
        s1 += __shfl_xor(s1, off, 64);
        s2 += __shfl_xor(s2, off, 64);
    }
    float mu = s1 * (1.0f / DD);
    float var = s2 * (1.0f / DD) - mu * mu;
    float rstd = rsqrtf(var + 1e-5f);
    float4 lg = *((const float4*)ln_g + lane);
    float4 lb = *((const float4*)ln_b + lane);
    float4 nv;
    nv.x = fmaxf((val.x - mu) * rstd * lg.x + lb.x, 0.f);
    nv.y = fmaxf((val.y - mu) * rstd * lg.y + lb.y, 0.f);
    nv.z = fmaxf((val.z - mu) * rstd * lg.z + lb.z, 0.f);
    nv.w = fmaxf((val.w - mu) * rstd * lg.w + lb.w, 0.f);
    float4* hp = (float4*)(h + (size_t)n * DD) + lane;
    float4 hv = *hp;
    hv.x += nv.x; hv.y += nv.y; hv.z += nv.z; hv.w += nv.w;
    *hp = hv;
    bf16x4 hb;
    hb[0] = (__bf16)hv.x; hb[1] = (__bf16)hv.y;
    hb[2] = (__bf16)hv.z; hb[3] = (__bf16)hv.w;
    *((bf16x4*)(hbf + (size_t)n * DD) + lane) = hb;
}

// ---------------------------------------------------------------------------
// K7a: per-graph gate max + denom; segment bounds via inline binary search.
__global__ __launch_bounds__(256) void gseg_kernel(
    const float* __restrict__ gate, const int* __restrict__ batch,
    float* __restrict__ gmax, float* __restrict__ gden, int N) {
    int b = blockIdx.x;
    int tid = threadIdx.x;
    __shared__ int bounds[2];
    if (tid < 2) {
        int target = b + tid;
        int lo = 0, hi = N;
        while (lo < hi) {
            int mid = (lo + hi) >> 1;
            if (batch[mid] < target) lo = mid + 1; else hi = mid;
        }
        bounds[tid] = lo;
    }
    __syncthreads();
    int s0 = bounds[0], s1 = bounds[1];
    __shared__ float red[256];
    float m = -1e30f;
    for (int i = s0 + tid; i < s1; i += 256) m = fmaxf(m, gate[i]);
    red[tid] = m;
    __syncthreads();
    for (int off = 128; off; off >>= 1) {
        if (tid < off) red[tid] = fmaxf(red[tid], red[tid + off]);
        __syncthreads();
    }
    float gm = red[0];
    __syncthreads();
    float s = 0.f;
    for (int i = s0 + tid; i < s1; i += 256) s += __expf(gate[i] - gm);
    red[tid] = s;
    __syncthreads();
    for (int off = 128; off; off >>= 1) {
        if (tid < off) red[tid] += red[tid + off];
        __syncthreads();
    }
    if (tid == 0) {
        gmax[b] = gm;
        gden[b] = red[0];
    }
}

// K7d: pooled embedding; softmax weight computed inline.
#define POOL_CHUNK 32
__global__ __launch_bounds__(256) void pool_scatter_kernel(
    const float* __restrict__ h, const float* __restrict__ gate,
    const float* __restrict__ gmax, const float* __restrict__ gden,
    const int* __restrict__ batch, float* __restrict__ g_embed, int N) {
    int i0 = blockIdx.x * POOL_CHUNK;
    int d = threadIdx.x;
    int iend = min(i0 + POOL_CHUNK, N);
    float acc = 0.f;
    int cur = batch[i0];
    for (int i = i0; i < iend; ++i) {
        int b = batch[i];
        if (b != cur) {
            atomicAdd(&g_embed[cur * DD + d], acc);
            acc = 0.f;
            cur = b;
        }
        float wgt = __expf(gate[i] - gmax[b]) / gden[b];
        acc += wgt * h[(size_t)i * DD + d];
    }
    atomicAdd(&g_embed[cur * DD + d], acc);
}

__global__ __launch_bounds__(256) void readout_kernel(
    const float* __restrict__ g_embed, const float* __restrict__ w1,
    const float* __restrict__ b1, const float* __restrict__ w2,
    const float* __restrict__ b2, float* __restrict__ out) {
    int b = blockIdx.x;
    int tid = threadIdx.x;
    __shared__ float gvec[256];
    __shared__ float hid[256];
    gvec[tid] = g_embed[b * DD + tid];
    __syncthreads();
    float hv = b1[tid];
    for (int k = 0; k < DD; ++k) hv += gvec[k] * w1[k * DD + tid];
    hid[tid] = fmaxf(hv, 0.f);
    __syncthreads();
    float o = b2[tid];
    for (int t = 0; t < DD; ++t) o += hid[t] * w2[t * DD + tid];
    out[b * DD + tid] = o;
}

// ---------------------------------------------------------------------------
extern "C" void kernel_launch(void* const* d_in, const int* in_sizes, int n_in,
                              void* d_out, int out_size, void* d_ws, size_t ws_size,
                              hipStream_t stream) {
    const float* x        = (const float*)d_in[0];
    const float* edge_attr= (const float*)d_in[1];
    const int*   edge_idx = (const int*)d_in[2];
    const int*   batch    = (const int*)d_in[3];
    const float* enc_w    = (const float*)d_in[4];
    const float* enc_b    = (const float*)d_in[5];
    const float* eenc_w   = (const float*)d_in[6];
    const float* eenc_b   = (const float*)d_in[7];
    const float* gat_w    = (const float*)d_in[8];
    const float* att_src  = (const float*)d_in[9];
    const float* att_dst  = (const float*)d_in[10];
    const float* att_edge = (const float*)d_in[11];
    const float* gat_ew   = (const float*)d_in[12];
    const float* gat_b    = (const float*)d_in[13];
    const float* ln_g     = (const float*)d_in[14];
    const float* ln_b     = (const float*)d_in[15];
    const float* gate_w1  = (const float*)d_in[16];
    const float* gate_b1  = (const float*)d_in[17];
    const float* gate_w2  = (const float*)d_in[18];
    const float* gate_b2  = (const float*)d_in[19];
    const float* ro_w1    = (const float*)d_in[20];
    const float* ro_b1    = (const float*)d_in[21];
    const float* ro_w2    = (const float*)d_in[22];
    const float* ro_b2    = (const float*)d_in[23];
    float* out = (float*)d_out;

    const int N = in_sizes[0] / 42;       // 10000
    const int E = in_sizes[1] / 12;       // 160000
    const int B = out_size / DD;          // 16

    // workspace carve-up
    char* p = (char*)d_ws;
    auto alloc = [&](size_t bytes) {
        char* r = p;
        p += (bytes + 255) & ~(size_t)255;
        return (void*)r;
    };
    float*  h       = (float*)alloc((size_t)N * DD * 4);
    __bf16* hbf     = (__bf16*)alloc((size_t)N * DD * 2);
    __bf16* xhbf    = (__bf16*)alloc((size_t)N * DD * 2);
    float*  a_s     = (float*)alloc((size_t)N * HH * 4);
    float*  a_d     = (float*)alloc((size_t)N * HH * 4);
    float*  a_e_csr = (float*)alloc((size_t)(E + N) * LH * 4);
    float*  wproj   = (float*)alloc((size_t)DD * LH * 4);
    __bf16* wfe     = (__bf16*)alloc((size_t)16 * 64 * 8 * 2);
    __bf16* wfp     = (__bf16*)alloc((size_t)16 * 64 * 8 * 2);
    __bf16* wf      = (__bf16*)alloc((size_t)6 * DD * DD * 2);
    float*  gate    = (float*)alloc((size_t)N * 4);
    float*  g_embed = (float*)alloc((size_t)B * DD * 4);
    float*  gmax    = (float*)alloc((size_t)B * 4);
    float*  gden    = (float*)alloc((size_t)B * 4);
    int* deg        = (int*)alloc((size_t)N * 4);
    int* row_ptr    = (int*)alloc((size_t)(N + 1) * 4);
    int* cursor     = (int*)alloc((size_t)N * 4);
    int* csr_src    = (int*)alloc((size_t)E * 4);
    int* pos        = (int*)alloc((size_t)E * 4);

    const int* src_arr = edge_idx;
    const int* dst_arr = edge_idx + E;

    hipMemsetAsync(deg, 0, (size_t)N * 4, stream);
    hipMemsetAsync(g_embed, 0, (size_t)B * DD * 4, stream);
    hipMemsetAsync(gate, 0, (size_t)N * 4, stream);

    wproj_kernel<<<LL, 256, 0, stream>>>(gat_ew, att_edge, wproj);
    pack_edge_frags_kernel<<<1, 256, 0, stream>>>(eenc_w, eenc_b, wproj, wfe, wfp);
    wswizzle_kernel<<<192, 256, 0, stream>>>(gat_w, gate_w1, wf);
    encoder_kernel<<<N, 256, 0, stream>>>(x, enc_w, enc_b, h, hbf, N);
    deg_kernel<<<(E + 255) / 256, 256, 0, stream>>>(dst_arr, deg, E);
    scan_kernel<<<1, 1024, 0, stream>>>(deg, row_ptr, cursor, N);
    scatter_kernel<<<(E + 255) / 256, 256, 0, stream>>>(
        src_arr, dst_arr, cursor, csr_src, pos, E);
    edge_mfma_kernel<<<(E + 63) / 64, 256, 0, stream>>>(
        edge_attr, wfe, wfp, pos, a_e_csr, E);
    self_ae_kernel<<<(N * LH + 255) / 256, 256, 0, stream>>>(
        row_ptr, a_e_csr, N, E);

    dim3 ggrid((N + 63) / 64, 2);
    for (int l = 0; l < LL; ++l) {
        gemm_mfma_kernel<<<ggrid, 256, 0, stream>>>(
            hbf, wf + (size_t)l * DD * DD, xhbf, N,
            att_src + l * DD, att_dst + l * DD, a_s, a_d,
            nullptr, nullptr, nullptr, nullptr);
        gat_message7_kernel<<<(N + 3) / 4, 256, 0, stream>>>(
            xhbf, a_s, a_d, a_e_csr + l * HH, row_ptr, csr_src,
            gat_b + l * DD, ln_g + l * DD, ln_b + l * DD, h, hbf, N, E);
    }

    // pooling gate: gate[n] = relu(h@gate_w1+b1) . gate_w2 + b2, fused MFMA
    gemm_mfma_kernel<<<ggrid, 256, 0, stream>>>(
        hbf, wf + (size_t)5 * DD * DD, nullptr, N,
        nullptr, nullptr, nullptr, nullptr,
        gate_b1, gate_w2, gate_b2, gate);
    gseg_kernel<<<B, 256, 0, stream>>>(gate, batch, gmax, gden, N);
    pool_scatter_kernel<<<(N + POOL_CHUNK - 1) / POOL_CHUNK, 256, 0, stream>>>(
        h, gate, gmax, gden, batch, g_embed, N);
    readout_kernel<<<B, 256, 0, stream>>>(g_embed, ro_w1, ro_b1, ro_w2, ro_b2, out);
}

// Round 17
// 402.584 us; speedup vs baseline: 1.1374x; 1.0648x over previous
//
#include <hip/hip_runtime.h>
#include <math.h>

// Problem constants (fixed-shape problem)
#define DD 256
#define HH 4
#define CC 64
#define LL 5
#define NEG_SLOPE 0.2f
#define LH 20   // L*H
#define WCAP 192  // per-wave LDS softmax-weight cache

typedef __bf16 bf16x8 __attribute__((ext_vector_type(8)));
typedef __bf16 bf16x4 __attribute__((ext_vector_type(4)));
typedef float f32x4 __attribute__((ext_vector_type(4)));

static __device__ __forceinline__ float lrelu(float x) {
    return x > 0.0f ? x : NEG_SLOPE * x;
}

// ---------------------------------------------------------------------------
// MEGA SETUP: independent prep work fused into one launch, partitioned by
// blockIdx range (each block takes exactly one branch):
//  [0,5)              wproj          (one layer per block)
//  [5,197)            wswizzle       (gat_w / gate_w1 -> MFMA B-frags)
//  [197,197+EB)       deg histogram  (EB = ceil(E/256))
//  [197+EB,197+EB+N)  encoder        (h, hbf)
//  [+0]               g_embed zero
//  [+1]               gate zero
__global__ __launch_bounds__(256) void mega_setup_kernel(
    const float* __restrict__ gat_ew, const float* __restrict__ att_edge,
    float* __restrict__ wproj,
    const float* __restrict__ gat_w, const float* __restrict__ gate_w1,
    __bf16* __restrict__ wf,
    const int* __restrict__ dst_arr, int* __restrict__ deg,
    const float* __restrict__ x, const float* __restrict__ enc_w,
    const float* __restrict__ enc_b, float* __restrict__ h,
    __bf16* __restrict__ hbf,
    float* __restrict__ g_embed, float* __restrict__ gate_out,
    int N, int E, int B) {
    int blk = blockIdx.x;
    int tid = threadIdx.x;
    int EB = (E + 255) >> 8;
    if (blk < 5) {
        // wproj
        int l = blk;
        int k = tid;
        const float* W = gat_ew + (size_t)l * DD * DD;
        const float* att = att_edge + l * DD;
        for (int hh = 0; hh < HH; ++hh) {
            float s = 0.f;
            #pragma unroll
            for (int c = 0; c < CC; ++c)
                s += W[k * DD + hh * CC + c] * att[hh * CC + c];
            wproj[k * LH + l * HH + hh] = s;
        }
        return;
    }
    blk -= 5;
    if (blk < 192) {
        // wswizzle
        int b = blk;
        int l = b >> 5;
        int rem = b & 31;
        int y = rem >> 3, ks = rem & 7;
        int t = tid >> 6, lane = tid & 63;
        int q = lane >> 4, r15 = lane & 15;
        const float* W = (l < 5) ? (gat_w + (size_t)l * DD * DD) : gate_w1;
        size_t obase = (((size_t)b * 4 + t) * 64 + lane) * 8;
        int kbase = ks * 32 + q * 8;
        int col = y * 64 + t * 16 + r15;
        #pragma unroll
        for (int j = 0; j < 8; ++j)
            wf[obase + j] = (__bf16)W[(size_t)(kbase + j) * DD + col];
        return;
    }
    blk -= 192;
    if (blk < EB) {
        int e = blk * 256 + tid;
        if (e < E) atomicAdd(&deg[dst_arr[e]], 1);
        return;
    }
    blk -= EB;
    if (blk < N) {
        // encoder
        int n = blk;
        __shared__ float xs[42];
        if (tid < 42) xs[tid] = x[(size_t)n * 42 + tid];
        __syncthreads();
        float acc = enc_b[tid];
        #pragma unroll
        for (int f = 0; f < 42; ++f) acc += xs[f] * enc_w[f * DD + tid];
        float v = fmaxf(acc, 0.f);
        h[(size_t)n * DD + tid] = v;
        hbf[(size_t)n * DD + tid] = (__bf16)v;
        return;
    }
    blk -= N;
    if (blk == 0) {
        for (int i = tid; i < B * DD; i += 256) g_embed[i] = 0.f;
        return;
    }
    // gate zero
    for (int i = tid; i < N; i += 256) gate_out[i] = 0.f;
}

// ---------------------------------------------------------------------------
// K4 v3: block 0 = shuffle-based exclusive scan (deg -> row_ptr + cursor);
// block 1 = pack edge-encoder + wproj MFMA B-fragments (bf16). Both depend
// only on mega_setup. 1024 threads.
__global__ __launch_bounds__(1024) void scan_pack_kernel(
    const int* __restrict__ deg, int* __restrict__ row_ptr,
    int* __restrict__ cursor, int n,
    const float* __restrict__ eenc_w, const float* __restrict__ eenc_b,
    const float* __restrict__ wproj, __bf16* __restrict__ wfe,
    __bf16* __restrict__ wfp) {
    int tid = threadIdx.x;
    if (blockIdx.x == 1) {
        // pack (1024 threads; exactly one idx each)
        {
            int idx = tid;
            int t = idx >> 6, lane = idx & 63;
            int q = lane >> 4, r15 = lane & 15;
            int col = t * 16 + r15;
            #pragma unroll
            for (int j = 0; j < 8; ++j) {
                int k = q * 8 + j;
                float v = (k < 12) ? eenc_w[k * 256 + col]
                                   : (k == 12 ? eenc_b[col] : 0.f);
                wfe[(size_t)idx * 8 + j] = (__bf16)v;
            }
        }
        {
            int idx = tid;
            int sidx = idx >> 6, lane = idx & 63;
            int s = sidx >> 1, t2 = sidx & 1;
            int q = lane >> 4, r15 = lane & 15;
            int col = t2 * 16 + r15;
            #pragma unroll
            for (int j = 0; j < 8; ++j) {
                int k = s * 32 + q * 8 + j;
                float v = (col < LH) ? wproj[k * LH + col] : 0.f;
                wfp[(size_t)idx * 8 + j] = (__bf16)v;
            }
        }
        return;
    }
    // scan
    __shared__ int wsum[16];
    __shared__ int carry_s;
    int w = tid >> 6, lane = tid & 63;
    if (tid == 0) carry_s = 0;
    __syncthreads();
    for (int base = 0; base < n; base += 1024) {
        int i = base + tid;
        int v = (i < n) ? deg[i] : 0;
        int carry = carry_s;
        int s = v;
        #pragma unroll
        for (int off = 1; off < 64; off <<= 1) {
            int t = __shfl_up(s, off, 64);
            if (lane >= off) s += t;
        }
        if (lane == 63) wsum[w] = s;
        __syncthreads();
        if (w == 0 && lane < 16) {
            int ws = wsum[lane];
            #pragma unroll
            for (int off = 1; off < 16; off <<= 1) {
                int t = __shfl_up(ws, off, 64);
                if (lane >= off) ws += t;
            }
            wsum[lane] = ws;
        }
        __syncthreads();
        int waveoff = (w == 0) ? 0 : wsum[w - 1];
        if (i < n) {
            int ex = carry + waveoff + s - v;
            row_ptr[i] = ex;
            cursor[i] = ex;
        }
        __syncthreads();
        if (tid == 0) carry_s = carry + wsum[15];
        __syncthreads();
    }
    if (tid == 0) row_ptr[n] = carry_s;
}

// K4c: scatter edges into CSR order by dst; emit inverse perm pos[e]
__global__ void scatter_kernel(const int* __restrict__ src, const int* __restrict__ dst,
                               int* __restrict__ cursor, int* __restrict__ csr_src,
                               int* __restrict__ pos, int E) {
    int e = blockIdx.x * 256 + threadIdx.x;
    if (e >= E) return;
    int d = dst[e];
    int pk = atomicAdd(&cursor[d], 1);
    csr_src[pk] = src[e];
    pos[e] = pk;
}

// ---------------------------------------------------------------------------
// K2 v6: edge_pre on matrix cores; output in CSR order via pos[e].
__global__ __launch_bounds__(256) void edge_mfma_kernel(
    const float* __restrict__ edge_attr, const __bf16* __restrict__ wfe,
    const __bf16* __restrict__ wfp, const int* __restrict__ pos,
    float* __restrict__ a_e_csr, int E) {
    __shared__ __bf16 sm[4][16][264];   // 33 KB
    int tid = threadIdx.x;
    int w = tid >> 6, lane = tid & 63;
    int q = lane >> 4, r15 = lane & 15;
    int eb = blockIdx.x * 64 + w * 16;
    int e = eb + r15;
    int ec = min(e, E - 1);
    bf16x8 a1;
    #pragma unroll
    for (int j = 0; j < 8; ++j) a1[j] = (__bf16)0.f;
    if (q == 0) {
        const float4* p = (const float4*)(edge_attr + (size_t)ec * 12);
        float4 p0 = p[0], p1 = p[1];
        a1[0] = (__bf16)p0.x; a1[1] = (__bf16)p0.y; a1[2] = (__bf16)p0.z; a1[3] = (__bf16)p0.w;
        a1[4] = (__bf16)p1.x; a1[5] = (__bf16)p1.y; a1[6] = (__bf16)p1.z; a1[7] = (__bf16)p1.w;
    } else if (q == 1) {
        float4 p2 = *(const float4*)(edge_attr + (size_t)ec * 12 + 8);
        a1[0] = (__bf16)p2.x; a1[1] = (__bf16)p2.y; a1[2] = (__bf16)p2.z; a1[3] = (__bf16)p2.w;
        a1[4] = (__bf16)1.0f;  // k = 12: bias row
    }
    const bf16x8* wfeP = (const bf16x8*)wfe;
    f32x4 zero = (f32x4){0.f, 0.f, 0.f, 0.f};
    #pragma unroll
    for (int t = 0; t < 16; ++t) {
        bf16x8 bfr = wfeP[t * 64 + lane];
        f32x4 c = __builtin_amdgcn_mfma_f32_16x16x32_bf16(a1, bfr, zero, 0, 0, 0);
        int col = t * 16 + r15;
        #pragma unroll
        for (int r = 0; r < 4; ++r)
            sm[w][q * 4 + r][col] = (__bf16)fmaxf(c[r], 0.f);
    }
    const bf16x8* wfpP = (const bf16x8*)wfp;
    f32x4 c2[2];
    c2[0] = zero; c2[1] = zero;
    #pragma unroll
    for (int s = 0; s < 8; ++s) {
        bf16x8 a2 = *(const bf16x8*)&sm[w][r15][s * 32 + q * 8];
        #pragma unroll
        for (int t2 = 0; t2 < 2; ++t2)
            c2[t2] = __builtin_amdgcn_mfma_f32_16x16x32_bf16(
                a2, wfpP[(s * 2 + t2) * 64 + lane], c2[t2], 0, 0, 0);
    }
    #pragma unroll
    for (int t2 = 0; t2 < 2; ++t2) {
        int col = t2 * 16 + r15;
        if (col >= LH) continue;
        #pragma unroll
        for (int r = 0; r < 4; ++r) {
            int e2 = eb + q * 4 + r;
            if (e2 < E) {
                int pk = pos[e2];
                a_e_csr[(size_t)pk * LH + col] = c2[t2][r];
            }
        }
    }
}

// K3: self-loop a_e = mean of incoming (contiguous CSR rows)
__global__ void self_ae_kernel(const int* __restrict__ row_ptr,
                               float* __restrict__ a_e_csr, int N, int E) {
    int i = blockIdx.x * 256 + threadIdx.x;
    if (i >= N * LH) return;
    int n = i / LH;
    int j = i % LH;
    int rs = row_ptr[n], re = row_ptr[n + 1];
    float s = 0.f;
    for (int k = rs; k < re; ++k)
        s += a_e_csr[(size_t)k * LH + j];
    a_e_csr[(size_t)(E + n) * LH + j] = s / (float)max(re - rs, 1);
}

// ---------------------------------------------------------------------------
// MFMA GEMM v2: 64 rows x 128 cols (2 heads) per block — halves hbf re-reads.
__global__ __launch_bounds__(256) void gemm_mfma_kernel(
    const __bf16* __restrict__ hbf, const __bf16* __restrict__ wf,
    __bf16* __restrict__ xhbf, int M,
    const float* __restrict__ att_src, const float* __restrict__ att_dst,
    float* __restrict__ a_s, float* __restrict__ a_d,
    const float* __restrict__ bias, const float* __restrict__ gate_w2,
    const float* __restrict__ gate_b2, float* __restrict__ gate_out) {
    int tid = threadIdx.x;
    int w = tid >> 6, lane = tid & 63;
    int q = lane >> 4, r15 = lane & 15;
    int m0 = blockIdx.x * 64;
    int y2 = blockIdx.y;          // head pair
    int arow = m0 + w * 16 + r15;
    int arowc = min(arow, M - 1);
    const __bf16* ap = hbf + (size_t)arowc * DD + q * 8;
    const bf16x8* wfP = (const bf16x8*)wf;
    f32x4 acc[8];
    #pragma unroll
    for (int g = 0; g < 8; ++g) acc[g] = (f32x4){0.f, 0.f, 0.f, 0.f};
    #pragma unroll
    for (int ks = 0; ks < 8; ++ks) {
        bf16x8 a = *(const bf16x8*)(ap + ks * 32);
        #pragma unroll
        for (int g = 0; g < 8; ++g) {
            int y = y2 * 2 + (g >> 2);   // head
            int t = g & 3;               // subtile within head
            bf16x8 b = wfP[(size_t)(((y * 8 + ks) * 4) + t) * 64 + lane];
            acc[g] = __builtin_amdgcn_mfma_f32_16x16x32_bf16(a, b, acc[g], 0, 0, 0);
        }
    }
    if (xhbf) {
        #pragma unroll
        for (int g = 0; g < 8; ++g) {
            int col = (y2 * 8 + g) * 16 + r15;
            #pragma unroll
            for (int r = 0; r < 4; ++r) {
                int rc = m0 + w * 16 + q * 4 + r;
                if (rc < M) xhbf[(size_t)rc * DD + col] = (__bf16)acc[g][r];
            }
        }
    }
    if (att_src) {
        #pragma unroll
        for (int r = 0; r < 4; ++r) {
            float ps0 = 0.f, pd0 = 0.f, ps1 = 0.f, pd1 = 0.f;
            #pragma unroll
            for (int g = 0; g < 8; ++g) {
                int col = (y2 * 8 + g) * 16 + r15;
                float v = acc[g][r];
                if (g < 4) { ps0 += v * att_src[col]; pd0 += v * att_dst[col]; }
                else       { ps1 += v * att_src[col]; pd1 += v * att_dst[col]; }
            }
            #pragma unroll
            for (int mask = 1; mask < 16; mask <<= 1) {
                ps0 += __shfl_xor(ps0, mask, 64);
                pd0 += __shfl_xor(pd0, mask, 64);
                ps1 += __shfl_xor(ps1, mask, 64);
                pd1 += __shfl_xor(pd1, mask, 64);
            }
            int rc = m0 + w * 16 + q * 4 + r;
            if (r15 == 0 && rc < M) {
                a_s[rc * HH + y2 * 2 + 0] = ps0;
                a_d[rc * HH + y2 * 2 + 0] = pd0;
                a_s[rc * HH + y2 * 2 + 1] = ps1;
                a_d[rc * HH + y2 * 2 + 1] = pd1;
            }
        }
    }
    if (gate_w2) {
        #pragma unroll
        for (int r = 0; r < 4; ++r) {
            float pg = 0.f;
            #pragma unroll
            for (int g = 0; g < 8; ++g) {
                int col = (y2 * 8 + g) * 16 + r15;
                pg += fmaxf(acc[g][r] + bias[col], 0.f) * gate_w2[col];
            }
            #pragma unroll
            for (int mask = 1; mask < 16; mask <<= 1) pg += __shfl_xor(pg, mask, 64);
            int rc = m0 + w * 16 + q * 4 + r;
            if (r15 == 0 && rc < M) {
                float add = pg + (y2 == 0 ? gate_b2[0] : 0.f);
                atomicAdd(&gate_out[rc], add);
            }
        }
    }
}

// ---------------------------------------------------------------------------
// K6 v7: WAVE-PER-NODE; CSR a_e; lsrc LDS cache; pass-3 unroll x2.
__global__ __launch_bounds__(256) void gat_message7_kernel(
    const __bf16* __restrict__ xhbf, const float* __restrict__ a_s,
    const float* __restrict__ a_d, const float* __restrict__ a_e,  // +l*4; [k][20]
    const int* __restrict__ row_ptr, const int* __restrict__ csr_src,
    const float* __restrict__ gat_b,
    const float* __restrict__ ln_g, const float* __restrict__ ln_b,
    float* __restrict__ h, __bf16* __restrict__ hbf, int N, int E) {
    __shared__ float lws[4][WCAP * 4];   // 12 KB
    __shared__ int lsrc[4][WCAP];        // 3 KB
    int tid = threadIdx.x;
    int w = tid >> 6, lane = tid & 63;
    int n = blockIdx.x * 4 + w;
    if (n >= N) return;
    int hh = lane >> 4, j = lane & 15;
    int rs = row_ptr[n], re = row_ptr[n + 1];
    int deg = re - rs;
    float adn = a_d[n * HH + hh];
    float al_self = lrelu(a_s[n * HH + hh] + adn + a_e[(size_t)(E + n) * LH + hh]);
    float m = al_self, den = 0.f;
    for (int k = rs + j; k < re; k += 16) {
        int kk = k - rs;
        int s = csr_src[k];
        float a = lrelu(a_s[s * HH + hh] + adn + a_e[(size_t)k * LH + hh]);
        if (kk < WCAP) {
            lws[w][kk * 4 + hh] = a;
            if (hh == 0) lsrc[w][kk] = s;
        }
        float mn = fmaxf(m, a);
        den = den * __expf(m - mn) + __expf(a - mn);
        m = mn;
    }
    #pragma unroll
    for (int off = 1; off < 16; off <<= 1) {
        float m2 = __shfl_xor(m, off, 64);
        float d2 = __shfl_xor(den, off, 64);
        float mn = fmaxf(m, m2);
        den = den * __expf(m - mn) + d2 * __expf(m2 - mn);
        m = mn;
    }
    den += __expf(al_self - m);
    float inv_den = 1.0f / den;
    int cap = min(deg, WCAP);
    for (int kk = j; kk < cap; kk += 16)
        lws[w][kk * 4 + hh] = __expf(lws[w][kk * 4 + hh] - m) * inv_den;
    float wself = __expf(al_self - m) * inv_den;
    bf16x4 xsb = *((const bf16x4*)(xhbf + (size_t)n * DD) + lane);
    float4 acc;
    acc.x = wself * (float)xsb[0]; acc.y = wself * (float)xsb[1];
    acc.z = wself * (float)xsb[2]; acc.w = wself * (float)xsb[3];
    int k = rs;
    for (; k + 1 < re; k += 2) {
        int kk0 = k - rs, kk1 = kk0 + 1;
        int s0, s1_;
        float w0, w1;
        if (kk1 < WCAP) {
            s0 = lsrc[w][kk0]; s1_ = lsrc[w][kk1];
            w0 = lws[w][kk0 * 4 + hh]; w1 = lws[w][kk1 * 4 + hh];
        } else {
            s0 = csr_src[k]; s1_ = csr_src[k + 1];
            w0 = (kk0 < WCAP) ? lws[w][kk0 * 4 + hh]
               : __expf(lrelu(a_s[s0 * HH + hh] + adn + a_e[(size_t)k * LH + hh]) - m) * inv_den;
            w1 = __expf(lrelu(a_s[s1_ * HH + hh] + adn + a_e[(size_t)(k + 1) * LH + hh]) - m) * inv_den;
        }
        bf16x4 x0 = *((const bf16x4*)(xhbf + (size_t)s0 * DD) + lane);
        bf16x4 x1 = *((const bf16x4*)(xhbf + (size_t)s1_ * DD) + lane);
        acc.x += w0 * (float)x0[0] + w1 * (float)x1[0];
        acc.y += w0 * (float)x0[1] + w1 * (float)x1[1];
        acc.z += w0 * (float)x0[2] + w1 * (float)x1[2];
        acc.w += w0 * (float)x0[3] + w1 * (float)x1[3];
    }
    if (k < re) {
        int kk0 = k - rs;
        int s0;
        float w0;
        if (kk0 < WCAP) { s0 = lsrc[w][kk0]; w0 = lws[w][kk0 * 4 + hh]; }
        else {
            s0 = csr_src[k];
            w0 = __expf(lrelu(a_s[s0 * HH + hh] + adn + a_e[(size_t)k * LH + hh]) - m) * inv_den;
        }
        bf16x4 x0 = *((const bf16x4*)(xhbf + (size_t)s0 * DD) + lane);
        acc.x += w0 * (float)x0[0]; acc.y += w0 * (float)x0[1];
        acc.z += w0 * (float)x0[2]; acc.w += w0 * (float)x0[3];
    }
    float4 gb = *((const float4*)gat_b + lane);
    float4 val;
    val.x = acc.x + gb.x; val.y = acc.y + gb.y;
    val.z = acc.z + gb.z; val.w = acc.w + gb.w;
    float s1 = val.x + val.y + val.z + val.w;
    float s2 = val.x * val.x + val.y * val.y + val.z * val.z + val.w * val.w;
    #pragma unroll
    for (int off = 1; off < 64; off <<= 1) {
        s1 += __shfl_xor(s1, off, 64);
        s2 += __shfl_xor(s2, off, 64);
    }
    float mu = s1 * (1.0f / DD);
    float var = s2 * (1.0f / DD) - mu * mu;
    float rstd = rsqrtf(var + 1e-5f);
    float4 lg = *((const float4*)ln_g + lane);
    float4 lb = *((const float4*)ln_b + lane);
    float4 nv;
    nv.x = fmaxf((val.x - mu) * rstd * lg.x + lb.x, 0.f);
    nv.y = fmaxf((val.y - mu) * rstd * lg.y + lb.y, 0.f);
    nv.z = fmaxf((val.z - mu) * rstd * lg.z + lb.z, 0.f);
    nv.w = fmaxf((val.w - mu) * rstd * lg.w + lb.w, 0.f);
    float4* hp = (float4*)(h + (size_t)n * DD) + lane;
    float4 hv = *hp;
    hv.x += nv.x; hv.y += nv.y; hv.z += nv.z; hv.w += nv.w;
    *hp = hv;
    bf16x4 hb;
    hb[0] = (__bf16)hv.x; hb[1] = (__bf16)hv.y;
    hb[2] = (__bf16)hv.z; hb[3] = (__bf16)hv.w;
    *((bf16x4*)(hbf + (size_t)n * DD) + lane) = hb;
}

// ---------------------------------------------------------------------------
// K7a: per-graph gate max + denom; segment bounds via inline binary search.
__global__ __launch_bounds__(256) void gseg_kernel(
    const float* __restrict__ gate, const int* __restrict__ batch,
    float* __restrict__ gmax, float* __restrict__ gden, int N) {
    int b = blockIdx.x;
    int tid = threadIdx.x;
    __shared__ int bounds[2];
    if (tid < 2) {
        int target = b + tid;
        int lo = 0, hi = N;
        while (lo < hi) {
            int mid = (lo + hi) >> 1;
            if (batch[mid] < target) lo = mid + 1; else hi = mid;
        }
        bounds[tid] = lo;
    }
    __syncthreads();
    int s0 = bounds[0], s1 = bounds[1];
    __shared__ float red[256];
    float m = -1e30f;
    for (int i = s0 + tid; i < s1; i += 256) m = fmaxf(m, gate[i]);
    red[tid] = m;
    __syncthreads();
    for (int off = 128; off; off >>= 1) {
        if (tid < off) red[tid] = fmaxf(red[tid], red[tid + off]);
        __syncthreads();
    }
    float gm = red[0];
    __syncthreads();
    float s = 0.f;
    for (int i = s0 + tid; i < s1; i += 256) s += __expf(gate[i] - gm);
    red[tid] = s;
    __syncthreads();
    for (int off = 128; off; off >>= 1) {
        if (tid < off) red[tid] += red[tid + off];
        __syncthreads();
    }
    if (tid == 0) {
        gmax[b] = gm;
        gden[b] = red[0];
    }
}

// K7d: pooled embedding; softmax weight computed inline.
#define POOL_CHUNK 32
__global__ __launch_bounds__(256) void pool_scatter_kernel(
    const float* __restrict__ h, const float* __restrict__ gate,
    const float* __restrict__ gmax, const float* __restrict__ gden,
    const int* __restrict__ batch, float* __restrict__ g_embed, int N) {
    int i0 = blockIdx.x * POOL_CHUNK;
    int d = threadIdx.x;
    int iend = min(i0 + POOL_CHUNK, N);
    float acc = 0.f;
    int cur = batch[i0];
    for (int i = i0; i < iend; ++i) {
        int b = batch[i];
        if (b != cur) {
            atomicAdd(&g_embed[cur * DD + d], acc);
            acc = 0.f;
            cur = b;
        }
        float wgt = __expf(gate[i] - gmax[b]) / gden[b];
        acc += wgt * h[(size_t)i * DD + d];
    }
    atomicAdd(&g_embed[cur * DD + d], acc);
}

__global__ __launch_bounds__(256) void readout_kernel(
    const float* __restrict__ g_embed, const float* __restrict__ w1,
    const float* __restrict__ b1, const float* __restrict__ w2,
    const float* __restrict__ b2, float* __restrict__ out) {
    int b = blockIdx.x;
    int tid = threadIdx.x;
    __shared__ float gvec[256];
    __shared__ float hid[256];
    gvec[tid] = g_embed[b * DD + tid];
    __syncthreads();
    float hv = b1[tid];
    for (int k = 0; k < DD; ++k) hv += gvec[k] * w1[k * DD + tid];
    hid[tid] = fmaxf(hv, 0.f);
    __syncthreads();
    float o = b2[tid];
    for (int t = 0; t < DD; ++t) o += hid[t] * w2[t * DD + tid];
    out[b * DD + tid] = o;
}

// ---------------------------------------------------------------------------
extern "C" void kernel_launch(void* const* d_in, const int* in_sizes, int n_in,
                              void* d_out, int out_size, void* d_ws, size_t ws_size,
                              hipStream_t stream) {
    const float* x        = (const float*)d_in[0];
    const float* edge_attr= (const float*)d_in[1];
    const int*   edge_idx = (const int*)d_in[2];
    const int*   batch    = (const int*)d_in[3];
    const float* enc_w    = (const float*)d_in[4];
    const float* enc_b    = (const float*)d_in[5];
    const float* eenc_w   = (const float*)d_in[6];
    const float* eenc_b   = (const float*)d_in[7];
    const float* gat_w    = (const float*)d_in[8];
    const float* att_src  = (const float*)d_in[9];
    const float* att_dst  = (const float*)d_in[10];
    const float* att_edge = (const float*)d_in[11];
    const float* gat_ew   = (const float*)d_in[12];
    const float* gat_b    = (const float*)d_in[13];
    const float* ln_g     = (const float*)d_in[14];
    const float* ln_b     = (const float*)d_in[15];
    const float* gate_w1  = (const float*)d_in[16];
    const float* gate_b1  = (const float*)d_in[17];
    const float* gate_w2  = (const float*)d_in[18];
    const float* gate_b2  = (const float*)d_in[19];
    const float* ro_w1    = (const float*)d_in[20];
    const float* ro_b1    = (const float*)d_in[21];
    const float* ro_w2    = (const float*)d_in[22];
    const float* ro_b2    = (const float*)d_in[23];
    float* out = (float*)d_out;

    const int N = in_sizes[0] / 42;       // 10000
    const int E = in_sizes[1] / 12;       // 160000
    const int B = out_size / DD;          // 16

    // workspace carve-up
    char* p = (char*)d_ws;
    auto alloc = [&](size_t bytes) {
        char* r = p;
        p += (bytes + 255) & ~(size_t)255;
        return (void*)r;
    };
    float*  h       = (float*)alloc((size_t)N * DD * 4);
    __bf16* hbf     = (__bf16*)alloc((size_t)N * DD * 2);
    __bf16* xhbf    = (__bf16*)alloc((size_t)N * DD * 2);
    float*  a_s     = (float*)alloc((size_t)N * HH * 4);
    float*  a_d     = (float*)alloc((size_t)N * HH * 4);
    float*  a_e_csr = (float*)alloc((size_t)(E + N) * LH * 4);
    float*  wproj   = (float*)alloc((size_t)DD * LH * 4);
    __bf16* wfe     = (__bf16*)alloc((size_t)16 * 64 * 8 * 2);
    __bf16* wfp     = (__bf16*)alloc((size_t)16 * 64 * 8 * 2);
    __bf16* wf      = (__bf16*)alloc((size_t)6 * DD * DD * 2);
    float*  gate    = (float*)alloc((size_t)N * 4);
    float*  g_embed = (float*)alloc((size_t)B * DD * 4);
    float*  gmax    = (float*)alloc((size_t)B * 4);
    float*  gden    = (float*)alloc((size_t)B * 4);
    int* deg        = (int*)alloc((size_t)N * 4);
    int* row_ptr    = (int*)alloc((size_t)(N + 1) * 4);
    int* cursor     = (int*)alloc((size_t)N * 4);
    int* csr_src    = (int*)alloc((size_t)E * 4);
    int* pos        = (int*)alloc((size_t)E * 4);

    const int* src_arr = edge_idx;
    const int* dst_arr = edge_idx + E;

    hipMemsetAsync(deg, 0, (size_t)N * 4, stream);

    const int EB = (E + 255) / 256;
    int mega_grid = 5 + 192 + EB + N + 2;
    mega_setup_kernel<<<mega_grid, 256, 0, stream>>>(
        gat_ew, att_edge, wproj, gat_w, gate_w1, wf,
        dst_arr, deg, x, enc_w, enc_b, h, hbf, g_embed, gate, N, E, B);
    scan_pack_kernel<<<2, 1024, 0, stream>>>(
        deg, row_ptr, cursor, N, eenc_w, eenc_b, wproj, wfe, wfp);
    scatter_kernel<<<(E + 255) / 256, 256, 0, stream>>>(
        src_arr, dst_arr, cursor, csr_src, pos, E);
    edge_mfma_kernel<<<(E + 63) / 64, 256, 0, stream>>>(
        edge_attr, wfe, wfp, pos, a_e_csr, E);
    self_ae_kernel<<<(N * LH + 255) / 256, 256, 0, stream>>>(
        row_ptr, a_e_csr, N, E);

    dim3 ggrid((N + 63) / 64, 2);
    for (int l = 0; l < LL; ++l) {
        gemm_mfma_kernel<<<ggrid, 256, 0, stream>>>(
            hbf, wf + (size_t)l * DD * DD, xhbf, N,
            att_src + l * DD, att_dst + l * DD, a_s, a_d,
            nullptr, nullptr, nullptr, nullptr);
        gat_message7_kernel<<<(N + 3) / 4, 256, 0, stream>>>(
            xhbf, a_s, a_d, a_e_csr + l * HH, row_ptr, csr_src,
            gat_b + l * DD, ln_g + l * DD, ln_b + l * DD, h, hbf, N, E);
    }

    // pooling gate: gate[n] = relu(h@gate_w1+b1) . gate_w2 + b2, fused MFMA
    gemm_mfma_kernel<<<ggrid, 256, 0, stream>>>(
        hbf, wf + (size_t)5 * DD * DD, nullptr, N,
        nullptr, nullptr, nullptr, nullptr,
        gate_b1, gate_w2, gate_b2, gate);
    gseg_kernel<<<B, 256, 0, stream>>>(gate, batch, gmax, gden, N);
    pool_scatter_kernel<<<(N + POOL_CHUNK - 1) / POOL_CHUNK, 256, 0, stream>>>(
        h, gate, gmax, gden, batch, g_embed, N);
    readout_kernel<<<B, 256, 0, stream>>>(g_embed, ro_w1, ro_b1, ro_w2, ro_b2, out);
}

// Round 18
// 373.353 us; speedup vs baseline: 1.2265x; 1.0783x over previous
//
#include <hip/hip_runtime.h>
#include <math.h>

// Problem constants (fixed-shape problem)
#define DD 256
#define HH 4
#define CC 64
#define LL 5
#define NEG_SLOPE 0.2f
#define LH 20   // L*H
#define WCAP 192  // per-wave LDS softmax-weight cache

typedef __bf16 bf16x8 __attribute__((ext_vector_type(8)));
typedef __bf16 bf16x4 __attribute__((ext_vector_type(4)));
typedef float f32x4 __attribute__((ext_vector_type(4)));

static __device__ __forceinline__ float lrelu(float x) {
    return x > 0.0f ? x : NEG_SLOPE * x;
}

// ---------------------------------------------------------------------------
// MEGA SETUP: independent prep fused into one launch, partitioned by blockIdx:
//  [0,5) wproj | [5,197) wswizzle | [197,197+EB) deg | [..+N) encoder |
//  [+0] g_embed zero | [+1] gate zero
__global__ __launch_bounds__(256) void mega_setup_kernel(
    const float* __restrict__ gat_ew, const float* __restrict__ att_edge,
    float* __restrict__ wproj,
    const float* __restrict__ gat_w, const float* __restrict__ gate_w1,
    __bf16* __restrict__ wf,
    const int* __restrict__ dst_arr, int* __restrict__ deg,
    const float* __restrict__ x, const float* __restrict__ enc_w,
    const float* __restrict__ enc_b, float* __restrict__ h,
    __bf16* __restrict__ hbf,
    float* __restrict__ g_embed, float* __restrict__ gate_out,
    int N, int E, int B) {
    int blk = blockIdx.x;
    int tid = threadIdx.x;
    int EB = (E + 255) >> 8;
    if (blk < 5) {
        int l = blk;
        int k = tid;
        const float* W = gat_ew + (size_t)l * DD * DD;
        const float* att = att_edge + l * DD;
        for (int hh = 0; hh < HH; ++hh) {
            float s = 0.f;
            #pragma unroll
            for (int c = 0; c < CC; ++c)
                s += W[k * DD + hh * CC + c] * att[hh * CC + c];
            wproj[k * LH + l * HH + hh] = s;
        }
        return;
    }
    blk -= 5;
    if (blk < 192) {
        int b = blk;
        int l = b >> 5;
        int rem = b & 31;
        int y = rem >> 3, ks = rem & 7;
        int t = tid >> 6, lane = tid & 63;
        int q = lane >> 4, r15 = lane & 15;
        const float* W = (l < 5) ? (gat_w + (size_t)l * DD * DD) : gate_w1;
        size_t obase = (((size_t)b * 4 + t) * 64 + lane) * 8;
        int kbase = ks * 32 + q * 8;
        int col = y * 64 + t * 16 + r15;
        #pragma unroll
        for (int j = 0; j < 8; ++j)
            wf[obase + j] = (__bf16)W[(size_t)(kbase + j) * DD + col];
        return;
    }
    blk -= 192;
    if (blk < EB) {
        int e = blk * 256 + tid;
        if (e < E) atomicAdd(&deg[dst_arr[e]], 1);
        return;
    }
    blk -= EB;
    if (blk < N) {
        int n = blk;
        __shared__ float xs[42];
        if (tid < 42) xs[tid] = x[(size_t)n * 42 + tid];
        __syncthreads();
        float acc = enc_b[tid];
        #pragma unroll
        for (int f = 0; f < 42; ++f) acc += xs[f] * enc_w[f * DD + tid];
        float v = fmaxf(acc, 0.f);
        h[(size_t)n * DD + tid] = v;
        hbf[(size_t)n * DD + tid] = (__bf16)v;
        return;
    }
    blk -= N;
    if (blk == 0) {
        for (int i = tid; i < B * DD; i += 256) g_embed[i] = 0.f;
        return;
    }
    for (int i = tid; i < N; i += 256) gate_out[i] = 0.f;
}

// ---------------------------------------------------------------------------
// K4 v3: block 0 = shuffle scan (deg -> row_ptr + cursor); block 1 = pack
// edge-encoder + wproj MFMA B-fragments (bf16).
__global__ __launch_bounds__(1024) void scan_pack_kernel(
    const int* __restrict__ deg, int* __restrict__ row_ptr,
    int* __restrict__ cursor, int n,
    const float* __restrict__ eenc_w, const float* __restrict__ eenc_b,
    const float* __restrict__ wproj, __bf16* __restrict__ wfe,
    __bf16* __restrict__ wfp) {
    int tid = threadIdx.x;
    if (blockIdx.x == 1) {
        {
            int idx = tid;
            int t = idx >> 6, lane = idx & 63;
            int q = lane >> 4, r15 = lane & 15;
            int col = t * 16 + r15;
            #pragma unroll
            for (int j = 0; j < 8; ++j) {
                int k = q * 8 + j;
                float v = (k < 12) ? eenc_w[k * 256 + col]
                                   : (k == 12 ? eenc_b[col] : 0.f);
                wfe[(size_t)idx * 8 + j] = (__bf16)v;
            }
        }
        {
            int idx = tid;
            int sidx = idx >> 6, lane = idx & 63;
            int s = sidx >> 1, t2 = sidx & 1;
            int q = lane >> 4, r15 = lane & 15;
            int col = t2 * 16 + r15;
            #pragma unroll
            for (int j = 0; j < 8; ++j) {
                int k = s * 32 + q * 8 + j;
                float v = (col < LH) ? wproj[k * LH + col] : 0.f;
                wfp[(size_t)idx * 8 + j] = (__bf16)v;
            }
        }
        return;
    }
    __shared__ int wsum[16];
    __shared__ int carry_s;
    int w = tid >> 6, lane = tid & 63;
    if (tid == 0) carry_s = 0;
    __syncthreads();
    for (int base = 0; base < n; base += 1024) {
        int i = base + tid;
        int v = (i < n) ? deg[i] : 0;
        int carry = carry_s;
        int s = v;
        #pragma unroll
        for (int off = 1; off < 64; off <<= 1) {
            int t = __shfl_up(s, off, 64);
            if (lane >= off) s += t;
        }
        if (lane == 63) wsum[w] = s;
        __syncthreads();
        if (w == 0 && lane < 16) {
            int ws = wsum[lane];
            #pragma unroll
            for (int off = 1; off < 16; off <<= 1) {
                int t = __shfl_up(ws, off, 64);
                if (lane >= off) ws += t;
            }
            wsum[lane] = ws;
        }
        __syncthreads();
        int waveoff = (w == 0) ? 0 : wsum[w - 1];
        if (i < n) {
            int ex = carry + waveoff + s - v;
            row_ptr[i] = ex;
            cursor[i] = ex;
        }
        __syncthreads();
        if (tid == 0) carry_s = carry + wsum[15];
        __syncthreads();
    }
    if (tid == 0) row_ptr[n] = carry_s;
}

// ---------------------------------------------------------------------------
// K2 v7: edge_pre on matrix cores WITH fused CSR scatter. Lanes q==0 do the
// cursor atomic + csr_src write; pk passed to writer lanes via wave-private
// LDS (same-wave ordering, no barrier). a_e layout: [l][E+N][4] so each
// layer's per-edge read is a dense 16 B row.
__global__ __launch_bounds__(256) void edge_mfma_kernel(
    const float* __restrict__ edge_attr, const __bf16* __restrict__ wfe,
    const __bf16* __restrict__ wfp,
    const int* __restrict__ src_arr, const int* __restrict__ dst_arr,
    int* __restrict__ cursor, int* __restrict__ csr_src,
    float* __restrict__ a_e, int E, int N) {
    __shared__ __bf16 sm[4][16][264];   // 33 KB
    __shared__ int pkbuf[4][16];
    int tid = threadIdx.x;
    int w = tid >> 6, lane = tid & 63;
    int q = lane >> 4, r15 = lane & 15;
    int eb = blockIdx.x * 64 + w * 16;
    int e = eb + r15;
    int ec = min(e, E - 1);
    // fused scatter: one lane per edge
    if (q == 0 && e < E) {
        int d = dst_arr[e];
        int pk = atomicAdd(&cursor[d], 1);
        csr_src[pk] = src_arr[e];
        pkbuf[w][r15] = pk;
    }
    bf16x8 a1;
    #pragma unroll
    for (int j = 0; j < 8; ++j) a1[j] = (__bf16)0.f;
    if (q == 0) {
        const float4* p = (const float4*)(edge_attr + (size_t)ec * 12);
        float4 p0 = p[0], p1 = p[1];
        a1[0] = (__bf16)p0.x; a1[1] = (__bf16)p0.y; a1[2] = (__bf16)p0.z; a1[3] = (__bf16)p0.w;
        a1[4] = (__bf16)p1.x; a1[5] = (__bf16)p1.y; a1[6] = (__bf16)p1.z; a1[7] = (__bf16)p1.w;
    } else if (q == 1) {
        float4 p2 = *(const float4*)(edge_attr + (size_t)ec * 12 + 8);
        a1[0] = (__bf16)p2.x; a1[1] = (__bf16)p2.y; a1[2] = (__bf16)p2.z; a1[3] = (__bf16)p2.w;
        a1[4] = (__bf16)1.0f;  // k = 12: bias row
    }
    const bf16x8* wfeP = (const bf16x8*)wfe;
    f32x4 zero = (f32x4){0.f, 0.f, 0.f, 0.f};
    #pragma unroll
    for (int t = 0; t < 16; ++t) {
        bf16x8 bfr = wfeP[t * 64 + lane];
        f32x4 c = __builtin_amdgcn_mfma_f32_16x16x32_bf16(a1, bfr, zero, 0, 0, 0);
        int col = t * 16 + r15;
        #pragma unroll
        for (int r = 0; r < 4; ++r)
            sm[w][q * 4 + r][col] = (__bf16)fmaxf(c[r], 0.f);
    }
    const bf16x8* wfpP = (const bf16x8*)wfp;
    f32x4 c2[2];
    c2[0] = zero; c2[1] = zero;
    #pragma unroll
    for (int s = 0; s < 8; ++s) {
        bf16x8 a2 = *(const bf16x8*)&sm[w][r15][s * 32 + q * 8];
        #pragma unroll
        for (int t2 = 0; t2 < 2; ++t2)
            c2[t2] = __builtin_amdgcn_mfma_f32_16x16x32_bf16(
                a2, wfpP[(s * 2 + t2) * 64 + lane], c2[t2], 0, 0, 0);
    }
    size_t stride_l = (size_t)(E + N) * 4;
    #pragma unroll
    for (int t2 = 0; t2 < 2; ++t2) {
        int col = t2 * 16 + r15;
        if (col >= LH) continue;
        int l = col >> 2, hh = col & 3;
        #pragma unroll
        for (int r = 0; r < 4; ++r) {
            int e2 = eb + q * 4 + r;
            if (e2 < E) {
                int pk = pkbuf[w][q * 4 + r];
                a_e[(size_t)l * stride_l + (size_t)pk * 4 + hh] = c2[t2][r];
            }
        }
    }
}

// K3: self-loop a_e = mean of incoming (contiguous CSR rows, [l][E+N][4])
__global__ void self_ae_kernel(const int* __restrict__ row_ptr,
                               float* __restrict__ a_e, int N, int E) {
    int i = blockIdx.x * 256 + threadIdx.x;
    if (i >= N * LH) return;
    int n = i / LH;
    int j = i % LH;
    int l = j >> 2, hh = j & 3;
    int rs = row_ptr[n], re = row_ptr[n + 1];
    size_t base = (size_t)l * (size_t)(E + N) * 4;
    float s = 0.f;
    for (int k = rs; k < re; ++k)
        s += a_e[base + (size_t)k * 4 + hh];
    a_e[base + (size_t)(E + n) * 4 + hh] = s / (float)max(re - rs, 1);
}

// ---------------------------------------------------------------------------
// MFMA GEMM v2: 64 rows x 128 cols (2 heads) per block.
__global__ __launch_bounds__(256) void gemm_mfma_kernel(
    const __bf16* __restrict__ hbf, const __bf16* __restrict__ wf,
    __bf16* __restrict__ xhbf, int M,
    const float* __restrict__ att_src, const float* __restrict__ att_dst,
    float* __restrict__ a_s, float* __restrict__ a_d,
    const float* __restrict__ bias, const float* __restrict__ gate_w2,
    const float* __restrict__ gate_b2, float* __restrict__ gate_out) {
    int tid = threadIdx.x;
    int w = tid >> 6, lane = tid & 63;
    int q = lane >> 4, r15 = lane & 15;
    int m0 = blockIdx.x * 64;
    int y2 = blockIdx.y;          // head pair
    int arow = m0 + w * 16 + r15;
    int arowc = min(arow, M - 1);
    const __bf16* ap = hbf + (size_t)arowc * DD + q * 8;
    const bf16x8* wfP = (const bf16x8*)wf;
    f32x4 acc[8];
    #pragma unroll
    for (int g = 0; g < 8; ++g) acc[g] = (f32x4){0.f, 0.f, 0.f, 0.f};
    #pragma unroll
    for (int ks = 0; ks < 8; ++ks) {
        bf16x8 a = *(const bf16x8*)(ap + ks * 32);
        #pragma unroll
        for (int g = 0; g < 8; ++g) {
            int y = y2 * 2 + (g >> 2);
            int t = g & 3;
            bf16x8 b = wfP[(size_t)(((y * 8 + ks) * 4) + t) * 64 + lane];
            acc[g] = __builtin_amdgcn_mfma_f32_16x16x32_bf16(a, b, acc[g], 0, 0, 0);
        }
    }
    if (xhbf) {
        #pragma unroll
        for (int g = 0; g < 8; ++g) {
            int col = (y2 * 8 + g) * 16 + r15;
            #pragma unroll
            for (int r = 0; r < 4; ++r) {
                int rc = m0 + w * 16 + q * 4 + r;
                if (rc < M) xhbf[(size_t)rc * DD + col] = (__bf16)acc[g][r];
            }
        }
    }
    if (att_src) {
        #pragma unroll
        for (int r = 0; r < 4; ++r) {
            float ps0 = 0.f, pd0 = 0.f, ps1 = 0.f, pd1 = 0.f;
            #pragma unroll
            for (int g = 0; g < 8; ++g) {
                int col = (y2 * 8 + g) * 16 + r15;
                float v = acc[g][r];
                if (g < 4) { ps0 += v * att_src[col]; pd0 += v * att_dst[col]; }
                else       { ps1 += v * att_src[col]; pd1 += v * att_dst[col]; }
            }
            #pragma unroll
            for (int mask = 1; mask < 16; mask <<= 1) {
                ps0 += __shfl_xor(ps0, mask, 64);
                pd0 += __shfl_xor(pd0, mask, 64);
                ps1 += __shfl_xor(ps1, mask, 64);
                pd1 += __shfl_xor(pd1, mask, 64);
            }
            int rc = m0 + w * 16 + q * 4 + r;
            if (r15 == 0 && rc < M) {
                a_s[rc * HH + y2 * 2 + 0] = ps0;
                a_d[rc * HH + y2 * 2 + 0] = pd0;
                a_s[rc * HH + y2 * 2 + 1] = ps1;
                a_d[rc * HH + y2 * 2 + 1] = pd1;
            }
        }
    }
    if (gate_w2) {
        #pragma unroll
        for (int r = 0; r < 4; ++r) {
            float pg = 0.f;
            #pragma unroll
            for (int g = 0; g < 8; ++g) {
                int col = (y2 * 8 + g) * 16 + r15;
                pg += fmaxf(acc[g][r] + bias[col], 0.f) * gate_w2[col];
            }
            #pragma unroll
            for (int mask = 1; mask < 16; mask <<= 1) pg += __shfl_xor(pg, mask, 64);
            int rc = m0 + w * 16 + q * 4 + r;
            if (r15 == 0 && rc < M) {
                float add = pg + (y2 == 0 ? gate_b2[0] : 0.f);
                atomicAdd(&gate_out[rc], add);
            }
        }
    }
}

// ---------------------------------------------------------------------------
// K6 v8: WAVE-PER-NODE; dense per-layer a_e rows ([E+N][4]); lsrc cache;
// cached-path pass 3 unrolled x4.
__global__ __launch_bounds__(256) void gat_message8_kernel(
    const __bf16* __restrict__ xhbf, const float* __restrict__ a_s,
    const float* __restrict__ a_d, const float* __restrict__ a_e,  // this layer; [E+N][4]
    const int* __restrict__ row_ptr, const int* __restrict__ csr_src,
    const float* __restrict__ gat_b,
    const float* __restrict__ ln_g, const float* __restrict__ ln_b,
    float* __restrict__ h, __bf16* __restrict__ hbf, int N, int E) {
    __shared__ float lws[4][WCAP * 4];   // 12 KB
    __shared__ int lsrc[4][WCAP];        // 3 KB
    int tid = threadIdx.x;
    int w = tid >> 6, lane = tid & 63;
    int n = blockIdx.x * 4 + w;
    if (n >= N) return;
    int hh = lane >> 4, j = lane & 15;
    int rs = row_ptr[n], re = row_ptr[n + 1];
    int deg = re - rs;
    float adn = a_d[n * HH + hh];
    float al_self = lrelu(a_s[n * HH + hh] + adn + a_e[(size_t)(E + n) * 4 + hh]);
    float m = al_self, den = 0.f;
    for (int k = rs + j; k < re; k += 16) {
        int kk = k - rs;
        int s = csr_src[k];
        float a = lrelu(a_s[s * HH + hh] + adn + a_e[(size_t)k * 4 + hh]);
        if (kk < WCAP) {
            lws[w][kk * 4 + hh] = a;
            if (hh == 0) lsrc[w][kk] = s;
        }
        float mn = fmaxf(m, a);
        den = den * __expf(m - mn) + __expf(a - mn);
        m = mn;
    }
    #pragma unroll
    for (int off = 1; off < 16; off <<= 1) {
        float m2 = __shfl_xor(m, off, 64);
        float d2 = __shfl_xor(den, off, 64);
        float mn = fmaxf(m, m2);
        den = den * __expf(m - mn) + d2 * __expf(m2 - mn);
        m = mn;
    }
    den += __expf(al_self - m);
    float inv_den = 1.0f / den;
    int cap = min(deg, WCAP);
    for (int kk = j; kk < cap; kk += 16)
        lws[w][kk * 4 + hh] = __expf(lws[w][kk * 4 + hh] - m) * inv_den;
    float wself = __expf(al_self - m) * inv_den;
    bf16x4 xsb = *((const bf16x4*)(xhbf + (size_t)n * DD) + lane);
    float4 acc;
    acc.x = wself * (float)xsb[0]; acc.y = wself * (float)xsb[1];
    acc.z = wself * (float)xsb[2]; acc.w = wself * (float)xsb[3];
    if (deg <= WCAP) {
        int k = rs;
        for (; k + 3 < re; k += 4) {
            int kk = k - rs;
            int s0 = lsrc[w][kk + 0], s1_ = lsrc[w][kk + 1];
            int s2_ = lsrc[w][kk + 2], s3_ = lsrc[w][kk + 3];
            float w0 = lws[w][(kk + 0) * 4 + hh], w1 = lws[w][(kk + 1) * 4 + hh];
            float w2 = lws[w][(kk + 2) * 4 + hh], w3 = lws[w][(kk + 3) * 4 + hh];
            bf16x4 x0 = *((const bf16x4*)(xhbf + (size_t)s0 * DD) + lane);
            bf16x4 x1 = *((const bf16x4*)(xhbf + (size_t)s1_ * DD) + lane);
            bf16x4 x2 = *((const bf16x4*)(xhbf + (size_t)s2_ * DD) + lane);
            bf16x4 x3 = *((const bf16x4*)(xhbf + (size_t)s3_ * DD) + lane);
            acc.x += w0 * (float)x0[0] + w1 * (float)x1[0] + w2 * (float)x2[0] + w3 * (float)x3[0];
            acc.y += w0 * (float)x0[1] + w1 * (float)x1[1] + w2 * (float)x2[1] + w3 * (float)x3[1];
            acc.z += w0 * (float)x0[2] + w1 * (float)x1[2] + w2 * (float)x2[2] + w3 * (float)x3[2];
            acc.w += w0 * (float)x0[3] + w1 * (float)x1[3] + w2 * (float)x2[3] + w3 * (float)x3[3];
        }
        for (; k < re; ++k) {
            int kk = k - rs;
            int s0 = lsrc[w][kk];
            float w0 = lws[w][kk * 4 + hh];
            bf16x4 x0 = *((const bf16x4*)(xhbf + (size_t)s0 * DD) + lane);
            acc.x += w0 * (float)x0[0]; acc.y += w0 * (float)x0[1];
            acc.z += w0 * (float)x0[2]; acc.w += w0 * (float)x0[3];
        }
    } else {
        for (int k = rs; k < re; ++k) {
            int kk = k - rs;
            int s0;
            float w0;
            if (kk < WCAP) { s0 = lsrc[w][kk]; w0 = lws[w][kk * 4 + hh]; }
            else {
                s0 = csr_src[k];
                w0 = __expf(lrelu(a_s[s0 * HH + hh] + adn + a_e[(size_t)k * 4 + hh]) - m) * inv_den;
            }
            bf16x4 x0 = *((const bf16x4*)(xhbf + (size_t)s0 * DD) + lane);
            acc.x += w0 * (float)x0[0]; acc.y += w0 * (float)x0[1];
            acc.z += w0 * (float)x0[2]; acc.w += w0 * (float)x0[3];
        }
    }
    float4 gb = *((const float4*)gat_b + lane);
    float4 val;
    val.x = acc.x + gb.x; val.y = acc.y + gb.y;
    val.z = acc.z + gb.z; val.w = acc.w + gb.w;
    float s1 = val.x + val.y + val.z + val.w;
    float s2 = val.x * val.x + val.y * val.y + val.z * val.z + val.w * val.w;
    #pragma unroll
    for (int off = 1; off < 64; off <<= 1) {
        s1 += __shfl_xor(s1, off, 64);
        s2 += __shfl_xor(s2, off, 64);
    }
    float mu = s1 * (1.0f / DD);
    float var = s2 * (1.0f / DD) - mu * mu;
    float rstd = rsqrtf(var + 1e-5f);
    float4 lg = *((const float4*)ln_g + lane);
    float4 lb = *((const float4*)ln_b + lane);
    float4 nv;
    nv.x = fmaxf((val.x - mu) * rstd * lg.x + lb.x, 0.f);
    nv.y = fmaxf((val.y - mu) * rstd * lg.y + lb.y, 0.f);
    nv.z = fmaxf((val.z - mu) * rstd * lg.z + lb.z, 0.f);
    nv.w = fmaxf((val.w - mu) * rstd * lg.w + lb.w, 0.f);
    float4* hp = (float4*)(h + (size_t)n * DD) + lane;
    float4 hv = *hp;
    hv.x += nv.x; hv.y += nv.y; hv.z += nv.z; hv.w += nv.w;
    *hp = hv;
    bf16x4 hb;
    hb[0] = (__bf16)hv.x; hb[1] = (__bf16)hv.y;
    hb[2] = (__bf16)hv.z; hb[3] = (__bf16)hv.w;
    *((bf16x4*)(hbf + (size_t)n * DD) + lane) = hb;
}

// ---------------------------------------------------------------------------
// K7a: per-graph gate max + denom; segment bounds via inline binary search.
__global__ __launch_bounds__(256) void gseg_kernel(
    const float* __restrict__ gate, const int* __restrict__ batch,
    float* __restrict__ gmax, float* __restrict__ gden, int N) {
    int b = blockIdx.x;
    int tid = threadIdx.x;
    __shared__ int bounds[2];
    if (tid < 2) {
        int target = b + tid;
        int lo = 0, hi = N;
        while (lo < hi) {
            int mid = (lo + hi) >> 1;
            if (batch[mid] < target) lo = mid + 1; else hi = mid;
        }
        bounds[tid] = lo;
    }
    __syncthreads();
    int s0 = bounds[0], s1 = bounds[1];
    __shared__ float red[256];
    float m = -1e30f;
    for (int i = s0 + tid; i < s1; i += 256) m = fmaxf(m, gate[i]);
    red[tid] = m;
    __syncthreads();
    for (int off = 128; off; off >>= 1) {
        if (tid < off) red[tid] = fmaxf(red[tid], red[tid + off]);
        __syncthreads();
    }
    float gm = red[0];
    __syncthreads();
    float s = 0.f;
    for (int i = s0 + tid; i < s1; i += 256) s += __expf(gate[i] - gm);
    red[tid] = s;
    __syncthreads();
    for (int off = 128; off; off >>= 1) {
        if (tid < off) red[tid] += red[tid + off];
        __syncthreads();
    }
    if (tid == 0) {
        gmax[b] = gm;
        gden[b] = red[0];
    }
}

// K7d: pooled embedding; softmax weight computed inline.
#define POOL_CHUNK 32
__global__ __launch_bounds__(256) void pool_scatter_kernel(
    const float* __restrict__ h, const float* __restrict__ gate,
    const float* __restrict__ gmax, const float* __restrict__ gden,
    const int* __restrict__ batch, float* __restrict__ g_embed, int N) {
    int i0 = blockIdx.x * POOL_CHUNK;
    int d = threadIdx.x;
    int iend = min(i0 + POOL_CHUNK, N);
    float acc = 0.f;
    int cur = batch[i0];
    for (int i = i0; i < iend; ++i) {
        int b = batch[i];
        if (b != cur) {
            atomicAdd(&g_embed[cur * DD + d], acc);
            acc = 0.f;
            cur = b;
        }
        float wgt = __expf(gate[i] - gmax[b]) / gden[b];
        acc += wgt * h[(size_t)i * DD + d];
    }
    atomicAdd(&g_embed[cur * DD + d], acc);
}

__global__ __launch_bounds__(256) void readout_kernel(
    const float* __restrict__ g_embed, const float* __restrict__ w1,
    const float* __restrict__ b1, const float* __restrict__ w2,
    const float* __restrict__ b2, float* __restrict__ out) {
    int b = blockIdx.x;
    int tid = threadIdx.x;
    __shared__ float gvec[256];
    __shared__ float hid[256];
    gvec[tid] = g_embed[b * DD + tid];
    __syncthreads();
    float hv = b1[tid];
    for (int k = 0; k < DD; ++k) hv += gvec[k] * w1[k * DD + tid];
    hid[tid] = fmaxf(hv, 0.f);
    __syncthreads();
    float o = b2[tid];
    for (int t = 0; t < DD; ++t) o += hid[t] * w2[t * DD + tid];
    out[b * DD + tid] = o;
}

// ---------------------------------------------------------------------------
extern "C" void kernel_launch(void* const* d_in, const int* in_sizes, int n_in,
                              void* d_out, int out_size, void* d_ws, size_t ws_size,
                              hipStream_t stream) {
    const float* x        = (const float*)d_in[0];
    const float* edge_attr= (const float*)d_in[1];
    const int*   edge_idx = (const int*)d_in[2];
    const int*   batch    = (const int*)d_in[3];
    const float* enc_w    = (const float*)d_in[4];
    const float* enc_b    = (const float*)d_in[5];
    const float* eenc_w   = (const float*)d_in[6];
    const float* eenc_b   = (const float*)d_in[7];
    const float* gat_w    = (const float*)d_in[8];
    const float* att_src  = (const float*)d_in[9];
    const float* att_dst  = (const float*)d_in[10];
    const float* att_edge = (const float*)d_in[11];
    const float* gat_ew   = (const float*)d_in[12];
    const float* gat_b    = (const float*)d_in[13];
    const float* ln_g     = (const float*)d_in[14];
    const float* ln_b     = (const float*)d_in[15];
    const float* gate_w1  = (const float*)d_in[16];
    const float* gate_b1  = (const float*)d_in[17];
    const float* gate_w2  = (const float*)d_in[18];
    const float* gate_b2  = (const float*)d_in[19];
    const float* ro_w1    = (const float*)d_in[20];
    const float* ro_b1    = (const float*)d_in[21];
    const float* ro_w2    = (const float*)d_in[22];
    const float* ro_b2    = (const float*)d_in[23];
    float* out = (float*)d_out;

    const int N = in_sizes[0] / 42;       // 10000
    const int E = in_sizes[1] / 12;       // 160000
    const int B = out_size / DD;          // 16

    // workspace carve-up
    char* p = (char*)d_ws;
    auto alloc = [&](size_t bytes) {
        char* r = p;
        p += (bytes + 255) & ~(size_t)255;
        return (void*)r;
    };
    float*  h       = (float*)alloc((size_t)N * DD * 4);
    __bf16* hbf     = (__bf16*)alloc((size_t)N * DD * 2);
    __bf16* xhbf    = (__bf16*)alloc((size_t)N * DD * 2);
    float*  a_s     = (float*)alloc((size_t)N * HH * 4);
    float*  a_d     = (float*)alloc((size_t)N * HH * 4);
    float*  a_e_csr = (float*)alloc((size_t)LL * (E + N) * 4 * 4);  // [l][E+N][4]
    float*  wproj   = (float*)alloc((size_t)DD * LH * 4);
    __bf16* wfe     = (__bf16*)alloc((size_t)16 * 64 * 8 * 2);
    __bf16* wfp     = (__bf16*)alloc((size_t)16 * 64 * 8 * 2);
    __bf16* wf      = (__bf16*)alloc((size_t)6 * DD * DD * 2);
    float*  gate    = (float*)alloc((size_t)N * 4);
    float*  g_embed = (float*)alloc((size_t)B * DD * 4);
    float*  gmax    = (float*)alloc((size_t)B * 4);
    float*  gden    = (float*)alloc((size_t)B * 4);
    int* deg        = (int*)alloc((size_t)N * 4);
    int* row_ptr    = (int*)alloc((size_t)(N + 1) * 4);
    int* cursor     = (int*)alloc((size_t)N * 4);
    int* csr_src    = (int*)alloc((size_t)E * 4);

    const int* src_arr = edge_idx;
    const int* dst_arr = edge_idx + E;

    hipMemsetAsync(deg, 0, (size_t)N * 4, stream);

    const int EB = (E + 255) / 256;
    int mega_grid = 5 + 192 + EB + N + 2;
    mega_setup_kernel<<<mega_grid, 256, 0, stream>>>(
        gat_ew, att_edge, wproj, gat_w, gate_w1, wf,
        dst_arr, deg, x, enc_w, enc_b, h, hbf, g_embed, gate, N, E, B);
    scan_pack_kernel<<<2, 1024, 0, stream>>>(
        deg, row_ptr, cursor, N, eenc_w, eenc_b, wproj, wfe, wfp);
    edge_mfma_kernel<<<(E + 63) / 64, 256, 0, stream>>>(
        edge_attr, wfe, wfp, src_arr, dst_arr, cursor, csr_src, a_e_csr, E, N);
    self_ae_kernel<<<(N * LH + 255) / 256, 256, 0, stream>>>(
        row_ptr, a_e_csr, N, E);

    dim3 ggrid((N + 63) / 64, 2);
    size_t lstride = (size_t)(E + N) * 4;
    for (int l = 0; l < LL; ++l) {
        gemm_mfma_kernel<<<ggrid, 256, 0, stream>>>(
            hbf, wf + (size_t)l * DD * DD, xhbf, N,
            att_src + l * DD, att_dst + l * DD, a_s, a_d,
            nullptr, nullptr, nullptr, nullptr);
        gat_message8_kernel<<<(N + 3) / 4, 256, 0, stream>>>(
            xhbf, a_s, a_d, a_e_csr + (size_t)l * lstride, row_ptr, csr_src,
            gat_b + l * DD, ln_g + l * DD, ln_b + l * DD, h, hbf, N, E);
    }

    // pooling gate: gate[n] = relu(h@gate_w1+b1) . gate_w2 + b2, fused MFMA
    gemm_mfma_kernel<<<ggrid, 256, 0, stream>>>(
        hbf, wf + (size_t)5 * DD * DD, nullptr, N,
        nullptr, nullptr, nullptr, nullptr,
        gate_b1, gate_w2, gate_b2, gate);
    gseg_kernel<<<B, 256, 0, stream>>>(gate, batch, gmax, gden, N);
    pool_scatter_kernel<<<(N + POOL_CHUNK - 1) / POOL_CHUNK, 256, 0, stream>>>(
        h, gate, gmax, gden, batch, g_embed, N);
    readout_kernel<<<B, 256, 0, stream>>>(g_embed, ro_w1, ro_b1, ro_w2, ro_b2, out);
}